// Round 4
// baseline (1142.432 us; speedup 1.0000x reference)
//
#include <hip/hip_runtime.h>

typedef unsigned short u16;
typedef unsigned int u32;
typedef __attribute__((ext_vector_type(8))) short bf16x8;
typedef __attribute__((ext_vector_type(4))) float f32x4;

#define N_NODES 524288
#define N_EDGES 4194304
#define N_GRAPH 16384

__device__ __forceinline__ float bf2f(u16 u){ u32 x=((u32)u)<<16; float f; __builtin_memcpy(&f,&x,4); return f; }
__device__ __forceinline__ float lo2f(u32 u){ u32 x=u<<16; float f; __builtin_memcpy(&f,&x,4); return f; }
__device__ __forceinline__ float hi2f(u32 u){ u32 x=u&0xffff0000u; float f; __builtin_memcpy(&f,&x,4); return f; }
__device__ __forceinline__ u16 f2bf(float f){ u32 x; __builtin_memcpy(&x,&f,4); return (u16)((x + 0x7fffu + ((x>>16)&1u))>>16); }
__device__ __forceinline__ float lrelu(float e){ return e>0.f? e : 0.2f*e; }
// dual-dtype external load: is32 ? fp32 : bf16
__device__ __forceinline__ float gload(const void* p, int i, int is32){
    return is32 ? ((const float*)p)[i] : bf2f(((const u16*)p)[i]);
}

// ---------------- input dtype detector ----------------
// bf16 data: bits14..7 of each u32 = exponent of low bf16 -> in [110,140] ~always.
// fp32 data: bits14..7 = middle mantissa bits -> ~12% in range.
__global__ __launch_bounds__(256) void k_detect(const u32* __restrict__ x, int* __restrict__ flag){
    __shared__ int cnt;
    if (threadIdx.x==0) cnt = 0;
    __syncthreads();
    int c = 0;
    for (int i = threadIdx.x; i < 1024; i += 256){
        u32 e = (x[i] >> 7) & 0xFF;
        if (e >= 110 && e <= 140) c++;
    }
    atomicAdd(&cnt, c);
    __syncthreads();
    if (threadIdx.x==0) *flag = (cnt < 512) ? 1 : 0;   // 1 = fp32 inputs
}

// ---------------- CSR build ----------------
__global__ __launch_bounds__(256) void k_hist(const int* __restrict__ dst, int* __restrict__ deg, int E){
    int e = blockIdx.x*256 + threadIdx.x;
    if (e < E) atomicAdd(&deg[dst[e] & (N_NODES-1)], 1);
}

__global__ __launch_bounds__(256) void k_scan1(int* __restrict__ data, int* __restrict__ bsums){
    __shared__ int sh[256];
    int b = blockIdx.x, t = threadIdx.x;
    int base = b*1024 + t*4;
    int4 v = *(const int4*)(data + base);
    int s = v.x+v.y+v.z+v.w;
    sh[t] = s; __syncthreads();
    for (int off=1; off<256; off<<=1){
        int xv = (t>=off)? sh[t-off] : 0; __syncthreads();
        sh[t] += xv; __syncthreads();
    }
    int excl = sh[t] - s;
    if (t==255) bsums[b] = sh[255];
    int4 o; o.x = excl; o.y = excl+v.x; o.z = o.y+v.y; o.w = o.z+v.z;
    *(int4*)(data + base) = o;
}

__global__ __launch_bounds__(256) void k_scan2(int* __restrict__ bsums){ // 512 entries, 1 block
    __shared__ int sh[256];
    int t = threadIdx.x;
    int v0 = bsums[2*t], v1 = bsums[2*t+1];
    int s = v0+v1; sh[t] = s; __syncthreads();
    for (int off=1; off<256; off<<=1){
        int xv = (t>=off)? sh[t-off] : 0; __syncthreads();
        sh[t] += xv; __syncthreads();
    }
    int excl = sh[t] - s;
    bsums[2*t] = excl; bsums[2*t+1] = excl + v0;
}

__global__ __launch_bounds__(256) void k_scan3(int* __restrict__ scan, const int* __restrict__ bsums, int N_, int E_){
    int i = blockIdx.x*256 + threadIdx.x;
    if (i < N_) scan[i] += bsums[i>>10];
    if (i == 0) scan[N_] = E_;
}

__global__ __launch_bounds__(256) void k_scatter(const int* __restrict__ src, const int* __restrict__ dst,
        const int* __restrict__ rowptr, int* __restrict__ cursor, int* __restrict__ ssrc, int E){
    int e = blockIdx.x*256 + threadIdx.x;
    if (e >= E) return;
    int d = dst[e] & (N_NODES-1);
    int pos = atomicAdd(&cursor[d], 1);
    u32 idx = (u32)(rowptr[d] + pos);
    if (idx < (u32)E) ssrc[idx] = src[e] & (N_NODES-1);
}

// ---------------- GAT node linears ----------------
__global__ __launch_bounds__(256) void k_linear1(const void* __restrict__ x,
        const void* __restrict__ W1, const void* __restrict__ asw, const void* __restrict__ adw,
        u16* __restrict__ h1, float* __restrict__ as1, float* __restrict__ ad1,
        const int* __restrict__ flag){
    int is32 = *flag;
    __shared__ float Wf[196], av[14], dv[14];
    int t = threadIdx.x;
    if (t < 196) Wf[t] = gload(W1, t, is32);
    else if (t < 210) av[t-196] = gload(asw, t-196, is32);
    else if (t < 224) dv[t-210] = gload(adw, t-210, is32);
    __syncthreads();
    int i = blockIdx.x*256 + t;
    float xv[14];
    if (is32){
        const float* xr = (const float*)x + (size_t)i*14;
        #pragma unroll
        for (int k=0;k<14;k++) xv[k] = xr[k];
    } else {
        const u32* xr = (const u32*)((const u16*)x + (size_t)i*14);
        #pragma unroll
        for (int p=0;p<7;p++){ u32 u = xr[p]; xv[2*p]=lo2f(u); xv[2*p+1]=hi2f(u); }
    }
    float h[14];
    #pragma unroll
    for (int j=0;j<14;j++){ float s=0.f;
        #pragma unroll
        for (int k=0;k<14;k++) s += xv[k]*Wf[k*14+j];
        h[j]=s; }
    float a=0.f, d=0.f;
    #pragma unroll
    for (int j=0;j<14;j++){ a += h[j]*av[j]; d += h[j]*dv[j]; }
    as1[i]=a; ad1[i]=d;
    u32 ou[8];
    #pragma unroll
    for (int p=0;p<7;p++) ou[p] = (u32)f2bf(h[2*p]) | ((u32)f2bf(h[2*p+1])<<16);
    ou[7]=0u;
    uint4* hp = (uint4*)(h1 + (size_t)i*16);
    hp[0] = make_uint4(ou[0],ou[1],ou[2],ou[3]);
    hp[1] = make_uint4(ou[4],ou[5],ou[6],ou[7]);
}

__global__ __launch_bounds__(256) void k_linear2(const u16* __restrict__ g1,
        const void* __restrict__ W2, const void* __restrict__ asw, const void* __restrict__ adw,
        u16* __restrict__ h2, float* __restrict__ as2, float* __restrict__ ad2,
        const int* __restrict__ flag){
    int is32 = *flag;
    __shared__ float Wf[448], av[32], dv[32];
    int t = threadIdx.x;
    for (int idx=t; idx<448; idx+=256) Wf[idx] = gload(W2, idx, is32);
    if (t < 32) { av[t] = gload(asw, t, is32); dv[t] = gload(adw, t, is32); }
    __syncthreads();
    int i = blockIdx.x*256 + t;
    const uint4* gp = (const uint4*)(g1 + (size_t)i*16);
    uint4 q0 = gp[0], q1 = gp[1];
    u32 u[8] = {q0.x,q0.y,q0.z,q0.w,q1.x,q1.y,q1.z,q1.w};
    float gv[14];
    #pragma unroll
    for (int k=0;k<14;k++){ u32 uu=u[k>>1]; gv[k] = (k&1)? hi2f(uu) : lo2f(uu); }
    float h[32];
    #pragma unroll
    for (int j=0;j<32;j++) h[j]=0.f;
    #pragma unroll
    for (int k=0;k<14;k++){ float g_ = gv[k];
        #pragma unroll
        for (int j=0;j<32;j++) h[j] += g_*Wf[k*32+j]; }
    float a=0.f, d=0.f;
    #pragma unroll
    for (int j=0;j<32;j++){ a += h[j]*av[j]; d += h[j]*dv[j]; }
    as2[i]=a; ad2[i]=d;
    u32 ou[16];
    #pragma unroll
    for (int p=0;p<16;p++) ou[p] = (u32)f2bf(h[2*p]) | ((u32)f2bf(h[2*p+1])<<16);
    uint4* hp = (uint4*)(h2 + (size_t)i*32);
    hp[0]=make_uint4(ou[0],ou[1],ou[2],ou[3]);
    hp[1]=make_uint4(ou[4],ou[5],ou[6],ou[7]);
    hp[2]=make_uint4(ou[8],ou[9],ou[10],ou[11]);
    hp[3]=make_uint4(ou[12],ou[13],ou[14],ou[15]);
}

// ---------------- GAT gather: two-pass softmax (max, then exp-sum), per dst node ----------------
__global__ __launch_bounds__(256) void k_gather1(const int* __restrict__ rowptr, const int* __restrict__ ssrc,
        const u16* __restrict__ h1, const float* __restrict__ as1, const float* __restrict__ ad1,
        const void* __restrict__ b1, u16* __restrict__ g1, const int* __restrict__ flag){
    int is32 = *flag;
    int i = blockIdx.x*256 + threadIdx.x;
    float adv = ad1[i];
    int beg = rowptr[i], end = rowptr[i+1];
    float m = lrelu(as1[i] + adv);
    for (int j=beg; j<end; j++) m = fmaxf(m, lrelu(as1[ssrc[j]] + adv));
    float acc[14], den;
    {
        float w = __expf(lrelu(as1[i] + adv) - m); den = w;
        const uint4* hp = (const uint4*)(h1 + (size_t)i*16);
        uint4 q0=hp[0], q1=hp[1];
        u32 u[8] = {q0.x,q0.y,q0.z,q0.w,q1.x,q1.y,q1.z,q1.w};
        #pragma unroll
        for (int f=0;f<14;f++){ u32 uu=u[f>>1]; acc[f] = w*((f&1)? hi2f(uu):lo2f(uu)); }
    }
    for (int j=beg; j<end; j++){
        int s = ssrc[j];
        float w = __expf(lrelu(as1[s] + adv) - m); den += w;
        const uint4* hp = (const uint4*)(h1 + (size_t)s*16);
        uint4 q0=hp[0], q1=hp[1];
        u32 u[8] = {q0.x,q0.y,q0.z,q0.w,q1.x,q1.y,q1.z,q1.w};
        #pragma unroll
        for (int f=0;f<14;f++){ u32 uu=u[f>>1]; acc[f] += w*((f&1)? hi2f(uu):lo2f(uu)); }
    }
    float inv = 1.0f/den;
    u32 ou[8];
    #pragma unroll
    for (int p=0;p<7;p++){
        float v0 = fmaxf(acc[2*p]*inv + gload(b1,2*p,is32), 0.f);
        float v1 = fmaxf(acc[2*p+1]*inv + gload(b1,2*p+1,is32), 0.f);
        ou[p] = (u32)f2bf(v0) | ((u32)f2bf(v1)<<16);
    }
    ou[7]=0u;
    uint4* gp = (uint4*)(g1 + (size_t)i*16);
    gp[0]=make_uint4(ou[0],ou[1],ou[2],ou[3]);
    gp[1]=make_uint4(ou[4],ou[5],ou[6],ou[7]);
}

__global__ __launch_bounds__(256) void k_gather2(const int* __restrict__ rowptr, const int* __restrict__ ssrc,
        const u16* __restrict__ h2, const float* __restrict__ as2, const float* __restrict__ ad2,
        const void* __restrict__ b2, u16* __restrict__ g2, const int* __restrict__ flag){
    int is32 = *flag;
    int i = blockIdx.x*256 + threadIdx.x;
    float adv = ad2[i];
    int beg = rowptr[i], end = rowptr[i+1];
    float m = lrelu(as2[i] + adv);
    for (int j=beg; j<end; j++) m = fmaxf(m, lrelu(as2[ssrc[j]] + adv));
    float acc[32], den;
    {
        float w = __expf(lrelu(as2[i] + adv) - m); den = w;
        const uint4* hp = (const uint4*)(h2 + (size_t)i*32);
        uint4 q0=hp[0], q1=hp[1], q2=hp[2], q3=hp[3];
        u32 u[16] = {q0.x,q0.y,q0.z,q0.w,q1.x,q1.y,q1.z,q1.w,q2.x,q2.y,q2.z,q2.w,q3.x,q3.y,q3.z,q3.w};
        #pragma unroll
        for (int f=0;f<32;f++){ u32 uu=u[f>>1]; acc[f] = w*((f&1)? hi2f(uu):lo2f(uu)); }
    }
    for (int j=beg; j<end; j++){
        int s = ssrc[j];
        float w = __expf(lrelu(as2[s] + adv) - m); den += w;
        const uint4* hp = (const uint4*)(h2 + (size_t)s*32);
        uint4 q0=hp[0], q1=hp[1], q2=hp[2], q3=hp[3];
        u32 u[16] = {q0.x,q0.y,q0.z,q0.w,q1.x,q1.y,q1.z,q1.w,q2.x,q2.y,q2.z,q2.w,q3.x,q3.y,q3.z,q3.w};
        #pragma unroll
        for (int f=0;f<32;f++){ u32 uu=u[f>>1]; acc[f] += w*((f&1)? hi2f(uu):lo2f(uu)); }
    }
    float inv = 1.0f/den;
    u32 ou[16];
    #pragma unroll
    for (int p=0;p<16;p++){
        float v0 = fmaxf(acc[2*p]*inv + gload(b2,2*p,is32), 0.f);
        float v1 = fmaxf(acc[2*p+1]*inv + gload(b2,2*p+1,is32), 0.f);
        ou[p] = (u32)f2bf(v0) | ((u32)f2bf(v1)<<16);
    }
    uint4* gp = (uint4*)(g2 + (size_t)i*32);
    gp[0]=make_uint4(ou[0],ou[1],ou[2],ou[3]);
    gp[1]=make_uint4(ou[4],ou[5],ou[6],ou[7]);
    gp[2]=make_uint4(ou[8],ou[9],ou[10],ou[11]);
    gp[3]=make_uint4(ou[12],ou[13],ou[14],ou[15]);
}

// ---------------- pool (batch is sorted; binary search per graph) ----------------
__device__ __forceinline__ int lbound(const int* __restrict__ a, int n, int v){
    int lo=0, hi=n;
    while (lo < hi){ int m = (lo+hi)>>1; if (a[m] < v) lo = m+1; else hi = m; }
    return lo;
}

__global__ __launch_bounds__(64) void k_pool(const u16* __restrict__ g2, const int* __restrict__ batch,
        u16* __restrict__ comb, int N_){
    int b = blockIdx.x;
    int t = threadIdx.x, f = t & 31, half = t >> 5;
    int lo = lbound(batch, N_, b);
    int hi = lbound(batch, N_, b+1);
    float acc = 0.f;
    for (int i = lo + half; i < hi; i += 2) acc += bf2f(g2[(size_t)i*32 + f]);
    acc += __shfl_xor(acc, 32);
    if (t < 32) comb[(size_t)b*432 + f] = f2bf(acc);
}

// ---------------- weight transpose (W[KxN] -> Wt[N x Kp] bf16, zero-pad K..Kp) ----------------
__global__ __launch_bounds__(256) void k_transpose(const void* __restrict__ W, u16* __restrict__ Wt,
        int K, int Kp, int Nc, const int* __restrict__ flag){
    int is32 = *flag;
    int idx = blockIdx.x*256 + threadIdx.x;
    if (idx >= Nc*Kp) return;
    int n = idx / Kp, k = idx - n*Kp;
    Wt[idx] = (k < K) ? f2bf(gload(W, k*Nc + n, is32)) : (u16)0;
}

// ---------------- fused GEMM + bias + BN + ReLU (bf16 MFMA, 128x128 tile) ----------------
__global__ __launch_bounds__(256) void k_gemm(const void* __restrict__ A, const u16* __restrict__ Wt,
        const void* __restrict__ bias, const void* __restrict__ bnp, void* __restrict__ out,
        int K, int Kp, int Nc, int ostride, int ooff, int do_relu,
        int afollow, int out32, const int* __restrict__ flag){
    int is32 = *flag;
    int a32 = afollow ? is32 : 0;
    __shared__ u16 As[128][40];
    __shared__ u16 Bs[128][40];
    int t = threadIdx.x;
    int lane = t & 63, wave = t >> 6;
    int bm = blockIdx.x * 128;
    int bn = blockIdx.y * 128;
    int mt = (wave & 1) * 64, nt = (wave >> 1) * 64;
    int quad = lane >> 4, fr = lane & 15;

    f32x4 zero = {0.f, 0.f, 0.f, 0.f};
    f32x4 acc[4][4];
    #pragma unroll
    for (int i=0;i<4;i++)
        #pragma unroll
        for (int j=0;j<4;j++) acc[i][j] = zero;

    int srow0 = t >> 2;          // 0..63
    int scol = (t & 3) * 8;      // 0,8,16,24

    for (int k0 = 0; k0 < Kp; k0 += 32){
        #pragma unroll
        for (int h2_=0; h2_<2; h2_++){
            int row = srow0 + h2_*64;
            int gk = k0 + scol;
            if (a32){
                float4 a0 = {0,0,0,0}, a1 = {0,0,0,0};
                if (gk + 8 <= K){
                    const float* ap = (const float*)A + (size_t)(bm+row)*K + gk;
                    a0 = *(const float4*)ap; a1 = *(const float4*)(ap+4);
                }
                u32 w0 = (u32)f2bf(a0.x) | ((u32)f2bf(a0.y)<<16);
                u32 w1 = (u32)f2bf(a0.z) | ((u32)f2bf(a0.w)<<16);
                u32 w2 = (u32)f2bf(a1.x) | ((u32)f2bf(a1.y)<<16);
                u32 w3 = (u32)f2bf(a1.z) | ((u32)f2bf(a1.w)<<16);
                *(uint4*)(&As[row][scol]) = make_uint4(w0,w1,w2,w3);
            } else {
                uint4 av = make_uint4(0,0,0,0);
                if (gk + 8 <= K) av = *(const uint4*)((const u16*)A + (size_t)(bm+row)*K + gk);
                *(uint4*)(&As[row][scol]) = av;
            }
            uint4 bv = make_uint4(0,0,0,0);
            if (bn + row < Nc) bv = *(const uint4*)(Wt + (size_t)(bn+row)*Kp + gk);
            *(uint4*)(&Bs[row][scol]) = bv;
        }
        __syncthreads();
        bf16x8 af[4], bfr[4];
        #pragma unroll
        for (int i=0;i<4;i++) af[i] = *(const bf16x8*)(&As[mt + i*16 + fr][quad*8]);
        #pragma unroll
        for (int j=0;j<4;j++) bfr[j] = *(const bf16x8*)(&Bs[nt + j*16 + fr][quad*8]);
        #pragma unroll
        for (int i=0;i<4;i++)
            #pragma unroll
            for (int j=0;j<4;j++)
                acc[i][j] = __builtin_amdgcn_mfma_f32_16x16x32_bf16(af[i], bfr[j], acc[i][j], 0, 0, 0);
        __syncthreads();
    }

    #pragma unroll
    for (int j=0;j<4;j++){
        int gn = bn + nt + j*16 + fr;
        if (gn >= Nc) continue;
        float bb = gload(bias, gn, is32);
        float scale = 1.f, shift = bb;
        if (bnp){
            float gm_ = gload(bnp, gn, is32), bt = gload(bnp, Nc+gn, is32);
            float mn = gload(bnp, 2*Nc+gn, is32), vr = gload(bnp, 3*Nc+gn, is32);
            scale = gm_ * rsqrtf(vr + 1e-5f);
            shift = (bb - mn)*scale + bt;
        }
        #pragma unroll
        for (int i=0;i<4;i++){
            #pragma unroll
            for (int r=0;r<4;r++){
                int gm = bm + mt + i*16 + quad*4 + r;
                float v = acc[i][j][r]*scale + shift;
                if (do_relu) v = fmaxf(v, 0.f);
                size_t oidx = (size_t)gm*ostride + ooff + gn;
                if (out32) ((float*)out)[oidx] = v;
                else       ((u16*)out)[oidx] = f2bf(v);
            }
        }
    }
}

// ---------------- final fcc2 (K=100, Nc=1) -> FP32 output ----------------
__global__ __launch_bounds__(256) void k_fcc2(const float* __restrict__ c1, const void* __restrict__ w,
        const void* __restrict__ b, float* __restrict__ outp, const int* __restrict__ flag){
    int is32 = *flag;
    __shared__ float wf[100];
    int t = threadIdx.x;
    if (t < 100) wf[t] = gload(w, t, is32);
    __syncthreads();
    int i = blockIdx.x*256 + t;
    const float* r = c1 + (size_t)i*100;
    float s = 0.f;
    #pragma unroll 4
    for (int k=0;k<100;k++) s += r[k]*wf[k];
    outp[i] = s + gload(b, 0, is32);
}

extern "C" void kernel_launch(void* const* d_in, const int* in_sizes, int n_in,
                              void* d_out, int out_size, void* d_ws, size_t ws_size,
                              hipStream_t stream){
    const int N = N_NODES, E = N_EDGES;
    const void* x    = d_in[0];
    const int* ei   = (const int*)d_in[1];
    const int* srcA = ei;
    const int* dstA = ei + E;
    const int* batch= (const int*)d_in[2];
    const void* fing = d_in[3];
    const void* tv   = d_in[4];
    const void* W1   = d_in[5];
    const void* as1w = d_in[6];
    const void* ad1w = d_in[7];
    const void* b1   = d_in[8];
    const void* W2   = d_in[9];
    const void* as2w = d_in[10];
    const void* ad2w = d_in[11];
    const void* b2   = d_in[12];
    const void* fc1w = d_in[13]; const void* fc1b = d_in[14]; const void* bn1 = d_in[15];
    const void* fc2w = d_in[16]; const void* fc2b = d_in[17]; const void* bn2 = d_in[18];
    const void* fc3w = d_in[19]; const void* fc3b = d_in[20]; const void* bn3 = d_in[21];
    const void* fc4w = d_in[22]; const void* fc4b = d_in[23]; const void* bn4 = d_in[24];
    const void* fccw = d_in[25]; const void* fccb = d_in[26]; const void* bnc = d_in[27];
    const void* fcc2w= d_in[28]; const void* fcc2b= d_in[29];

    char* ws = (char*)d_ws;
    size_t off = 0;
    auto alloc = [&](size_t bytes)->char*{ char* p = ws + off; off = (off + bytes + 255) & ~(size_t)255; return p; };
    int*  flagp  = (int*)alloc(256);
    int*  rowptr = (int*)alloc((size_t)(N+1)*4);
    int*  cursor = (int*)alloc((size_t)N*4);
    int*  bsums  = (int*)alloc(513*4);
    int*  ssrc   = (int*)alloc((size_t)E*4);       // 16 MB; comb aliases after gathers
    u16*  h1     = (u16*)alloc((size_t)N*16*2);    // g2 aliases [h1|g1]
    u16*  g1     = (u16*)alloc((size_t)N*16*2);
    float* as_   = (float*)alloc((size_t)N*4);
    float* ad_   = (float*)alloc((size_t)N*4);
    u16*  h2     = (u16*)alloc((size_t)N*32*2);    // 32 MB; fp1/tv1 alias after gather2
    float* c1    = (float*)alloc((size_t)N_GRAPH*100*4);
    u16*  Wt1    = (u16*)alloc((size_t)400*1024*2);
    u16*  Wt2    = (u16*)alloc((size_t)200*416*2);
    u16*  Wt3    = (u16*)alloc((size_t)400*256*2);
    u16*  Wt4    = (u16*)alloc((size_t)200*416*2);
    u16*  Wtc    = (u16*)alloc((size_t)100*448*2);
    u16*  g2     = h1;                              // N*32 elems, spans h1+g1 (contiguous)
    u16*  comb   = (u16*)ssrc;                      // 16384*432*2 = 13.5 MB <= 16 MB
    u16*  fp1    = h2;                              // 16384*400*2 = 12.5 MB
    u16*  tv1    = h2 + (size_t)N_GRAPH*400;        // next 12.5 MB (<= 32 MB total)

    (void)hipMemsetAsync(rowptr, 0, (size_t)(N+1)*4, stream);
    (void)hipMemsetAsync(cursor, 0, (size_t)N*4, stream);
    (void)hipMemsetAsync(ssrc,   0, (size_t)E*4, stream);

    k_detect <<<1, 256, 0, stream>>>((const u32*)x, flagp);

    k_hist   <<<E/256, 256, 0, stream>>>(dstA, rowptr, E);
    k_scan1  <<<512,   256, 0, stream>>>(rowptr, bsums);
    k_scan2  <<<1,     256, 0, stream>>>(bsums);
    k_scan3  <<<N/256, 256, 0, stream>>>(rowptr, bsums, N, E);
    k_scatter<<<E/256, 256, 0, stream>>>(srcA, dstA, rowptr, cursor, ssrc, E);

    k_linear1<<<N/256, 256, 0, stream>>>(x, W1, as1w, ad1w, h1, as_, ad_, flagp);
    k_gather1<<<N/256, 256, 0, stream>>>(rowptr, ssrc, h1, as_, ad_, b1, g1, flagp);
    k_linear2<<<N/256, 256, 0, stream>>>(g1, W2, as2w, ad2w, h2, as_, ad_, flagp);
    k_gather2<<<N/256, 256, 0, stream>>>(rowptr, ssrc, h2, as_, ad_, b2, g2, flagp);
    k_pool   <<<N_GRAPH, 64, 0, stream>>>(g2, batch, comb, N);

    k_transpose<<<(400*1024+255)/256, 256, 0, stream>>>(fc1w, Wt1, 1024, 1024, 400, flagp);
    k_transpose<<<(200*416 +255)/256, 256, 0, stream>>>(fc2w, Wt2,  400,  416, 200, flagp);
    k_transpose<<<(400*256 +255)/256, 256, 0, stream>>>(fc3w, Wt3,  256,  256, 400, flagp);
    k_transpose<<<(200*416 +255)/256, 256, 0, stream>>>(fc4w, Wt4,  400,  416, 200, flagp);
    k_transpose<<<(100*448 +255)/256, 256, 0, stream>>>(fccw, Wtc,  432,  448, 100, flagp);

    // (A, Wt, bias, bn, out, K, Kp, Nc, ostride, ooff, relu, afollow, out32); M = 16384 -> grid.x = 128
    k_gemm<<<dim3(128,4), 256, 0, stream>>>(fing, Wt1, fc1b, bn1, fp1, 1024, 1024, 400, 400,   0, 1, 1, 0, flagp);
    k_gemm<<<dim3(128,2), 256, 0, stream>>>(fp1,  Wt2, fc2b, bn2, comb, 400,  416, 200, 432,  32, 1, 0, 0, flagp);
    k_gemm<<<dim3(128,4), 256, 0, stream>>>(tv,   Wt3, fc3b, bn3, tv1,  256,  256, 400, 400,   0, 1, 1, 0, flagp);
    k_gemm<<<dim3(128,2), 256, 0, stream>>>(tv1,  Wt4, fc4b, bn4, comb, 400,  416, 200, 432, 232, 1, 0, 0, flagp);
    k_gemm<<<dim3(128,1), 256, 0, stream>>>(comb, Wtc, fccb, bnc, c1,   432,  448, 100, 100,   0, 1, 0, 1, flagp);

    k_fcc2<<<N_GRAPH/256, 256, 0, stream>>>(c1, fcc2w, fcc2b, (float*)d_out, flagp);
}

// Round 5
// 1023.876 us; speedup vs baseline: 1.1158x; 1.1158x over previous
//
#include <hip/hip_runtime.h>

typedef unsigned short u16;
typedef unsigned int u32;
typedef __attribute__((ext_vector_type(8))) short bf16x8;
typedef __attribute__((ext_vector_type(4))) float f32x4;

#define N_NODES 524288
#define N_EDGES 4194304
#define N_GRAPH 16384

__device__ __forceinline__ float bf2f(u16 u){ u32 x=((u32)u)<<16; float f; __builtin_memcpy(&f,&x,4); return f; }
__device__ __forceinline__ float lo2f(u32 u){ u32 x=u<<16; float f; __builtin_memcpy(&f,&x,4); return f; }
__device__ __forceinline__ float hi2f(u32 u){ u32 x=u&0xffff0000u; float f; __builtin_memcpy(&f,&x,4); return f; }
__device__ __forceinline__ u16 f2bf(float f){ u32 x; __builtin_memcpy(&x,&f,4); return (u16)((x + 0x7fffu + ((x>>16)&1u))>>16); }
__device__ __forceinline__ float lrelu(float e){ return e>0.f? e : 0.2f*e; }
__device__ __forceinline__ float gload(const void* p, int i, int is32){
    return is32 ? ((const float*)p)[i] : bf2f(((const u16*)p)[i]);
}
// monotone float<->u32 key for atomicMax over floats
__device__ __forceinline__ u32 fmax_key(float f){ u32 u; __builtin_memcpy(&u,&f,4); return (u>>31)? ~u : (u|0x80000000u); }
__device__ __forceinline__ float key_fmax(u32 k){ u32 u = (k>>31)? (k^0x80000000u) : ~k; float f; __builtin_memcpy(&f,&u,4); return f; }

// ---------------- input dtype detector ----------------
__global__ __launch_bounds__(256) void k_detect(const u32* __restrict__ x, int* __restrict__ flag){
    __shared__ int cnt;
    if (threadIdx.x==0) cnt = 0;
    __syncthreads();
    int c = 0;
    for (int i = threadIdx.x; i < 1024; i += 256){
        u32 e = (x[i] >> 7) & 0xFF;
        if (e >= 110 && e <= 140) c++;
    }
    atomicAdd(&cnt, c);
    __syncthreads();
    if (threadIdx.x==0) *flag = (cnt < 512) ? 1 : 0;   // 1 = fp32 inputs
}

// ---------------- CSR build ----------------
// hist also captures each edge's rank within its dst (atomicAdd return), stored coalesced.
__global__ __launch_bounds__(256) void k_hist(const int* __restrict__ dst, int* __restrict__ deg,
        int* __restrict__ rank, int E){
    int e = blockIdx.x*256 + threadIdx.x;
    if (e < E){
        int d = __builtin_nontemporal_load(dst+e) & (N_NODES-1);
        int r = atomicAdd(&deg[d], 1);
        __builtin_nontemporal_store(r, rank+e);
    }
}

__global__ __launch_bounds__(256) void k_scan1(int* __restrict__ data, int* __restrict__ bsums){
    __shared__ int sh[256];
    int b = blockIdx.x, t = threadIdx.x;
    int base = b*1024 + t*4;
    int4 v = *(const int4*)(data + base);
    int s = v.x+v.y+v.z+v.w;
    sh[t] = s; __syncthreads();
    for (int off=1; off<256; off<<=1){
        int xv = (t>=off)? sh[t-off] : 0; __syncthreads();
        sh[t] += xv; __syncthreads();
    }
    int excl = sh[t] - s;
    if (t==255) bsums[b] = sh[255];
    int4 o; o.x = excl; o.y = excl+v.x; o.z = o.y+v.y; o.w = o.z+v.z;
    *(int4*)(data + base) = o;
}

__global__ __launch_bounds__(256) void k_scan2(int* __restrict__ bsums){ // 512 entries, 1 block
    __shared__ int sh[256];
    int t = threadIdx.x;
    int v0 = bsums[2*t], v1 = bsums[2*t+1];
    int s = v0+v1; sh[t] = s; __syncthreads();
    for (int off=1; off<256; off<<=1){
        int xv = (t>=off)? sh[t-off] : 0; __syncthreads();
        sh[t] += xv; __syncthreads();
    }
    int excl = sh[t] - s;
    bsums[2*t] = excl; bsums[2*t+1] = excl + v0;
}

__global__ __launch_bounds__(256) void k_scan3(int* __restrict__ scan, const int* __restrict__ bsums, int N_, int E_){
    int i = blockIdx.x*256 + threadIdx.x;
    if (i < N_) scan[i] += bsums[i>>10];
    if (i == 0) scan[N_] = E_;
}

// pure scatter: no atomics; nontemporal read streams so ssrc write lines stay in L2
__global__ __launch_bounds__(256) void k_scatter(const int* __restrict__ src, const int* __restrict__ dst,
        const int* __restrict__ rank, const int* __restrict__ rowptr, int* __restrict__ ssrc, int E){
    int e = blockIdx.x*256 + threadIdx.x;
    if (e >= E) return;
    int d = __builtin_nontemporal_load(dst+e) & (N_NODES-1);
    int r = __builtin_nontemporal_load(rank+e);
    int s = __builtin_nontemporal_load(src+e) & (N_NODES-1);
    u32 idx = (u32)(rowptr[d] + r);
    if (idx < (u32)E) ssrc[idx] = s;
}

// ---------------- GAT node linears (also reduce global max of a_src score) ----------------
__global__ __launch_bounds__(256) void k_linear1(const void* __restrict__ x,
        const void* __restrict__ W1, const void* __restrict__ asw, const void* __restrict__ adw,
        u16* __restrict__ h1, float* __restrict__ ad1, u32* __restrict__ gkey,
        const int* __restrict__ flag){
    int is32 = *flag;
    __shared__ float Wf[196], av[14], dv[14];
    __shared__ float red[256];
    int t = threadIdx.x;
    if (t < 196) Wf[t] = gload(W1, t, is32);
    else if (t < 210) av[t-196] = gload(asw, t-196, is32);
    else if (t < 224) dv[t-210] = gload(adw, t-210, is32);
    __syncthreads();
    int i = blockIdx.x*256 + t;
    float xv[14];
    if (is32){
        const float* xr = (const float*)x + (size_t)i*14;
        #pragma unroll
        for (int k=0;k<14;k++) xv[k] = xr[k];
    } else {
        const u32* xr = (const u32*)((const u16*)x + (size_t)i*14);
        #pragma unroll
        for (int p=0;p<7;p++){ u32 u = xr[p]; xv[2*p]=lo2f(u); xv[2*p+1]=hi2f(u); }
    }
    float h[14];
    #pragma unroll
    for (int j=0;j<14;j++){ float s=0.f;
        #pragma unroll
        for (int k=0;k<14;k++) s += xv[k]*Wf[k*14+j];
        h[j]=s; }
    float a=0.f, d=0.f;
    #pragma unroll
    for (int j=0;j<14;j++){ a += h[j]*av[j]; d += h[j]*dv[j]; }
    ad1[i]=d;
    u32 ou[8];
    #pragma unroll
    for (int p=0;p<7;p++) ou[p] = (u32)f2bf(h[2*p]) | ((u32)f2bf(h[2*p+1])<<16);
    __builtin_memcpy(&ou[7], &a, 4);   // fp32 a_src score packed in slots 14..15
    uint4* hp = (uint4*)(h1 + (size_t)i*16);
    hp[0] = make_uint4(ou[0],ou[1],ou[2],ou[3]);
    hp[1] = make_uint4(ou[4],ou[5],ou[6],ou[7]);
    // block max of a -> one atomic per block
    red[t] = a; __syncthreads();
    for (int o=128;o;o>>=1){ if (t<o) red[t]=fmaxf(red[t],red[t+o]); __syncthreads(); }
    if (t==0) atomicMax(gkey, fmax_key(red[0]));
}

__global__ __launch_bounds__(256) void k_linear2(const u16* __restrict__ g1,
        const void* __restrict__ W2, const void* __restrict__ asw, const void* __restrict__ adw,
        u16* __restrict__ h2, float* __restrict__ as2, float* __restrict__ ad2,
        u32* __restrict__ gkey, const int* __restrict__ flag){
    int is32 = *flag;
    __shared__ float Wf[448], av[32], dv[32];
    __shared__ float red[256];
    int t = threadIdx.x;
    for (int idx=t; idx<448; idx+=256) Wf[idx] = gload(W2, idx, is32);
    if (t < 32) { av[t] = gload(asw, t, is32); dv[t] = gload(adw, t, is32); }
    __syncthreads();
    int i = blockIdx.x*256 + t;
    const uint4* gp = (const uint4*)(g1 + (size_t)i*16);
    uint4 q0 = gp[0], q1 = gp[1];
    u32 u[8] = {q0.x,q0.y,q0.z,q0.w,q1.x,q1.y,q1.z,q1.w};
    float gv[14];
    #pragma unroll
    for (int k=0;k<14;k++){ u32 uu=u[k>>1]; gv[k] = (k&1)? hi2f(uu) : lo2f(uu); }
    float h[32];
    #pragma unroll
    for (int j=0;j<32;j++) h[j]=0.f;
    #pragma unroll
    for (int k=0;k<14;k++){ float g_ = gv[k];
        #pragma unroll
        for (int j=0;j<32;j++) h[j] += g_*Wf[k*32+j]; }
    float a=0.f, d=0.f;
    #pragma unroll
    for (int j=0;j<32;j++){ a += h[j]*av[j]; d += h[j]*dv[j]; }
    as2[i]=a; ad2[i]=d;
    u32 ou[16];
    #pragma unroll
    for (int p=0;p<16;p++) ou[p] = (u32)f2bf(h[2*p]) | ((u32)f2bf(h[2*p+1])<<16);
    uint4* hp = (uint4*)(h2 + (size_t)i*32);
    hp[0]=make_uint4(ou[0],ou[1],ou[2],ou[3]);
    hp[1]=make_uint4(ou[4],ou[5],ou[6],ou[7]);
    hp[2]=make_uint4(ou[8],ou[9],ou[10],ou[11]);
    hp[3]=make_uint4(ou[12],ou[13],ou[14],ou[15]);
    red[t] = a; __syncthreads();
    for (int o=128;o;o>>=1){ if (t<o) red[t]=fmaxf(red[t],red[t+o]); __syncthreads(); }
    if (t==0) atomicMax(gkey, fmax_key(red[0]));
}

// ---------------- GAT gather: single pass, global-max-bound softmax ----------------
__global__ __launch_bounds__(256) void k_gather1(const int* __restrict__ rowptr, const int* __restrict__ ssrc,
        const u16* __restrict__ h1, const float* __restrict__ ad1, const u32* __restrict__ gkey,
        const void* __restrict__ b1, u16* __restrict__ g1, const int* __restrict__ flag){
    int is32 = *flag;
    int i = blockIdx.x*256 + threadIdx.x;
    float adv = ad1[i];
    float M = lrelu(key_fmax(*gkey) + adv);   // upper bound of all e for this dst
    int beg = rowptr[i], end = rowptr[i+1];
    float acc[14], den;
    {
        const uint4* hp = (const uint4*)(h1 + (size_t)i*16);
        uint4 q0=hp[0], q1=hp[1];
        float as_; __builtin_memcpy(&as_, &q1.w, 4);
        float w = __expf(lrelu(as_ + adv) - M); den = w;
        u32 u[7] = {q0.x,q0.y,q0.z,q0.w,q1.x,q1.y,q1.z};
        #pragma unroll
        for (int f=0;f<14;f++){ u32 uu=u[f>>1]; acc[f] = w*((f&1)? hi2f(uu):lo2f(uu)); }
    }
    for (int j=beg; j<end; j++){
        int s = __builtin_nontemporal_load(ssrc+j);
        const uint4* hp = (const uint4*)(h1 + (size_t)s*16);
        uint4 q0=hp[0], q1=hp[1];
        float as_; __builtin_memcpy(&as_, &q1.w, 4);
        float w = __expf(lrelu(as_ + adv) - M); den += w;
        u32 u[7] = {q0.x,q0.y,q0.z,q0.w,q1.x,q1.y,q1.z};
        #pragma unroll
        for (int f=0;f<14;f++){ u32 uu=u[f>>1]; acc[f] += w*((f&1)? hi2f(uu):lo2f(uu)); }
    }
    float inv = 1.0f/den;
    u32 ou[8];
    #pragma unroll
    for (int p=0;p<7;p++){
        float v0 = fmaxf(acc[2*p]*inv + gload(b1,2*p,is32), 0.f);
        float v1 = fmaxf(acc[2*p+1]*inv + gload(b1,2*p+1,is32), 0.f);
        ou[p] = (u32)f2bf(v0) | ((u32)f2bf(v1)<<16);
    }
    ou[7]=0u;
    uint4* gp = (uint4*)(g1 + (size_t)i*16);
    gp[0]=make_uint4(ou[0],ou[1],ou[2],ou[3]);
    gp[1]=make_uint4(ou[4],ou[5],ou[6],ou[7]);
}

__global__ __launch_bounds__(256) void k_gather2(const int* __restrict__ rowptr, const int* __restrict__ ssrc,
        const u16* __restrict__ h2, const float* __restrict__ as2, const float* __restrict__ ad2,
        const u32* __restrict__ gkey, const void* __restrict__ b2, u16* __restrict__ g2,
        const int* __restrict__ flag){
    int is32 = *flag;
    int i = blockIdx.x*256 + threadIdx.x;
    float adv = ad2[i];
    float M = lrelu(key_fmax(*gkey) + adv);
    int beg = rowptr[i], end = rowptr[i+1];
    float acc[32], den;
    {
        float w = __expf(lrelu(as2[i] + adv) - M); den = w;
        const uint4* hp = (const uint4*)(h2 + (size_t)i*32);
        uint4 q0=hp[0], q1=hp[1], q2=hp[2], q3=hp[3];
        u32 u[16] = {q0.x,q0.y,q0.z,q0.w,q1.x,q1.y,q1.z,q1.w,q2.x,q2.y,q2.z,q2.w,q3.x,q3.y,q3.z,q3.w};
        #pragma unroll
        for (int f=0;f<32;f++){ u32 uu=u[f>>1]; acc[f] = w*((f&1)? hi2f(uu):lo2f(uu)); }
    }
    for (int j=beg; j<end; j++){
        int s = __builtin_nontemporal_load(ssrc+j);
        float w = __expf(lrelu(as2[s] + adv) - M); den += w;
        const uint4* hp = (const uint4*)(h2 + (size_t)s*32);
        uint4 q0=hp[0], q1=hp[1], q2=hp[2], q3=hp[3];
        u32 u[16] = {q0.x,q0.y,q0.z,q0.w,q1.x,q1.y,q1.z,q1.w,q2.x,q2.y,q2.z,q2.w,q3.x,q3.y,q3.z,q3.w};
        #pragma unroll
        for (int f=0;f<32;f++){ u32 uu=u[f>>1]; acc[f] += w*((f&1)? hi2f(uu):lo2f(uu)); }
    }
    float inv = 1.0f/den;
    u32 ou[16];
    #pragma unroll
    for (int p=0;p<16;p++){
        float v0 = fmaxf(acc[2*p]*inv + gload(b2,2*p,is32), 0.f);
        float v1 = fmaxf(acc[2*p+1]*inv + gload(b2,2*p+1,is32), 0.f);
        ou[p] = (u32)f2bf(v0) | ((u32)f2bf(v1)<<16);
    }
    uint4* gp = (uint4*)(g2 + (size_t)i*32);
    gp[0]=make_uint4(ou[0],ou[1],ou[2],ou[3]);
    gp[1]=make_uint4(ou[4],ou[5],ou[6],ou[7]);
    gp[2]=make_uint4(ou[8],ou[9],ou[10],ou[11]);
    gp[3]=make_uint4(ou[12],ou[13],ou[14],ou[15]);
}

// ---------------- pool (batch is sorted; binary search per graph) ----------------
__device__ __forceinline__ int lbound(const int* __restrict__ a, int n, int v){
    int lo=0, hi=n;
    while (lo < hi){ int m = (lo+hi)>>1; if (a[m] < v) lo = m+1; else hi = m; }
    return lo;
}

__global__ __launch_bounds__(64) void k_pool(const u16* __restrict__ g2, const int* __restrict__ batch,
        u16* __restrict__ comb, int N_){
    int b = blockIdx.x;
    int t = threadIdx.x, f = t & 31, half = t >> 5;
    int lo = lbound(batch, N_, b);
    int hi = lbound(batch, N_, b+1);
    float acc = 0.f;
    for (int i = lo + half; i < hi; i += 2) acc += bf2f(g2[(size_t)i*32 + f]);
    acc += __shfl_xor(acc, 32);
    if (t < 32) comb[(size_t)b*432 + f] = f2bf(acc);
}

// ---------------- weight transpose (W[KxN] -> Wt[N x Kp] bf16, zero-pad K..Kp) ----------------
__global__ __launch_bounds__(256) void k_transpose(const void* __restrict__ W, u16* __restrict__ Wt,
        int K, int Kp, int Nc, const int* __restrict__ flag){
    int is32 = *flag;
    int idx = blockIdx.x*256 + threadIdx.x;
    if (idx >= Nc*Kp) return;
    int n = idx / Kp, k = idx - n*Kp;
    Wt[idx] = (k < K) ? f2bf(gload(W, k*Nc + n, is32)) : (u16)0;
}

// ---------------- fused GEMM + bias + BN + ReLU (bf16 MFMA, 128x128 tile) ----------------
__global__ __launch_bounds__(256) void k_gemm(const void* __restrict__ A, const u16* __restrict__ Wt,
        const void* __restrict__ bias, const void* __restrict__ bnp, void* __restrict__ out,
        int K, int Kp, int Nc, int ostride, int ooff, int do_relu,
        int afollow, int out32, const int* __restrict__ flag){
    int is32 = *flag;
    int a32 = afollow ? is32 : 0;
    __shared__ u16 As[128][40];
    __shared__ u16 Bs[128][40];
    int t = threadIdx.x;
    int lane = t & 63, wave = t >> 6;
    int bm = blockIdx.x * 128;
    int bn = blockIdx.y * 128;
    int mt = (wave & 1) * 64, nt = (wave >> 1) * 64;
    int quad = lane >> 4, fr = lane & 15;

    f32x4 zero = {0.f, 0.f, 0.f, 0.f};
    f32x4 acc[4][4];
    #pragma unroll
    for (int i=0;i<4;i++)
        #pragma unroll
        for (int j=0;j<4;j++) acc[i][j] = zero;

    int srow0 = t >> 2;          // 0..63
    int scol = (t & 3) * 8;      // 0,8,16,24

    for (int k0 = 0; k0 < Kp; k0 += 32){
        #pragma unroll
        for (int h2_=0; h2_<2; h2_++){
            int row = srow0 + h2_*64;
            int gk = k0 + scol;
            if (a32){
                float4 a0 = {0,0,0,0}, a1 = {0,0,0,0};
                if (gk + 8 <= K){
                    const float* ap = (const float*)A + (size_t)(bm+row)*K + gk;
                    a0 = *(const float4*)ap; a1 = *(const float4*)(ap+4);
                }
                u32 w0 = (u32)f2bf(a0.x) | ((u32)f2bf(a0.y)<<16);
                u32 w1 = (u32)f2bf(a0.z) | ((u32)f2bf(a0.w)<<16);
                u32 w2 = (u32)f2bf(a1.x) | ((u32)f2bf(a1.y)<<16);
                u32 w3 = (u32)f2bf(a1.z) | ((u32)f2bf(a1.w)<<16);
                *(uint4*)(&As[row][scol]) = make_uint4(w0,w1,w2,w3);
            } else {
                uint4 av = make_uint4(0,0,0,0);
                if (gk + 8 <= K) av = *(const uint4*)((const u16*)A + (size_t)(bm+row)*K + gk);
                *(uint4*)(&As[row][scol]) = av;
            }
            uint4 bv = make_uint4(0,0,0,0);
            if (bn + row < Nc) bv = *(const uint4*)(Wt + (size_t)(bn+row)*Kp + gk);
            *(uint4*)(&Bs[row][scol]) = bv;
        }
        __syncthreads();
        bf16x8 af[4], bfr[4];
        #pragma unroll
        for (int i=0;i<4;i++) af[i] = *(const bf16x8*)(&As[mt + i*16 + fr][quad*8]);
        #pragma unroll
        for (int j=0;j<4;j++) bfr[j] = *(const bf16x8*)(&Bs[nt + j*16 + fr][quad*8]);
        #pragma unroll
        for (int i=0;i<4;i++)
            #pragma unroll
            for (int j=0;j<4;j++)
                acc[i][j] = __builtin_amdgcn_mfma_f32_16x16x32_bf16(af[i], bfr[j], acc[i][j], 0, 0, 0);
        __syncthreads();
    }

    #pragma unroll
    for (int j=0;j<4;j++){
        int gn = bn + nt + j*16 + fr;
        if (gn >= Nc) continue;
        float bb = gload(bias, gn, is32);
        float scale = 1.f, shift = bb;
        if (bnp){
            float gm_ = gload(bnp, gn, is32), bt = gload(bnp, Nc+gn, is32);
            float mn = gload(bnp, 2*Nc+gn, is32), vr = gload(bnp, 3*Nc+gn, is32);
            scale = gm_ * rsqrtf(vr + 1e-5f);
            shift = (bb - mn)*scale + bt;
        }
        #pragma unroll
        for (int i=0;i<4;i++){
            #pragma unroll
            for (int r=0;r<4;r++){
                int gm = bm + mt + i*16 + quad*4 + r;
                float v = acc[i][j][r]*scale + shift;
                if (do_relu) v = fmaxf(v, 0.f);
                size_t oidx = (size_t)gm*ostride + ooff + gn;
                if (out32) ((float*)out)[oidx] = v;
                else       ((u16*)out)[oidx] = f2bf(v);
            }
        }
    }
}

// ---------------- final fcc2 (K=100, Nc=1) -> FP32 output ----------------
__global__ __launch_bounds__(256) void k_fcc2(const float* __restrict__ c1, const void* __restrict__ w,
        const void* __restrict__ b, float* __restrict__ outp, const int* __restrict__ flag){
    int is32 = *flag;
    __shared__ float wf[100];
    int t = threadIdx.x;
    if (t < 100) wf[t] = gload(w, t, is32);
    __syncthreads();
    int i = blockIdx.x*256 + t;
    const float* r = c1 + (size_t)i*100;
    float s = 0.f;
    #pragma unroll 4
    for (int k=0;k<100;k++) s += r[k]*wf[k];
    outp[i] = s + gload(b, 0, is32);
}

extern "C" void kernel_launch(void* const* d_in, const int* in_sizes, int n_in,
                              void* d_out, int out_size, void* d_ws, size_t ws_size,
                              hipStream_t stream){
    const int N = N_NODES, E = N_EDGES;
    const void* x    = d_in[0];
    const int* ei   = (const int*)d_in[1];
    const int* srcA = ei;
    const int* dstA = ei + E;
    const int* batch= (const int*)d_in[2];
    const void* fing = d_in[3];
    const void* tv   = d_in[4];
    const void* W1   = d_in[5];
    const void* as1w = d_in[6];
    const void* ad1w = d_in[7];
    const void* b1   = d_in[8];
    const void* W2   = d_in[9];
    const void* as2w = d_in[10];
    const void* ad2w = d_in[11];
    const void* b2   = d_in[12];
    const void* fc1w = d_in[13]; const void* fc1b = d_in[14]; const void* bn1 = d_in[15];
    const void* fc2w = d_in[16]; const void* fc2b = d_in[17]; const void* bn2 = d_in[18];
    const void* fc3w = d_in[19]; const void* fc3b = d_in[20]; const void* bn3 = d_in[21];
    const void* fc4w = d_in[22]; const void* fc4b = d_in[23]; const void* bn4 = d_in[24];
    const void* fccw = d_in[25]; const void* fccb = d_in[26]; const void* bnc = d_in[27];
    const void* fcc2w= d_in[28]; const void* fcc2b= d_in[29];

    char* ws = (char*)d_ws;
    size_t off = 0;
    auto alloc = [&](size_t bytes)->char*{ char* p = ws + off; off = (off + bytes + 255) & ~(size_t)255; return p; };
    int*  flagp  = (int*)alloc(256);          // [0]=dtype flag; [1]=gkey1; [2]=gkey2
    u32*  gkey1  = (u32*)flagp + 1;
    u32*  gkey2  = (u32*)flagp + 2;
    int*  rowptr = (int*)alloc((size_t)(N+1)*4);
    int*  bsums  = (int*)alloc(513*4);
    int*  ssrc   = (int*)alloc((size_t)E*4);       // 16 MB; comb aliases after gathers
    u16*  h1     = (u16*)alloc((size_t)N*16*2);    // g2 aliases [h1|g1]
    u16*  g1     = (u16*)alloc((size_t)N*16*2);
    float* ad1_  = (float*)alloc((size_t)N*4);
    float* as2_  = (float*)alloc((size_t)N*4);
    float* ad2_  = (float*)alloc((size_t)N*4);
    u16*  h2     = (u16*)alloc((size_t)N*32*2);    // 32 MB; rank + fp1/tv1 alias
    float* c1    = (float*)alloc((size_t)N_GRAPH*100*4);
    u16*  Wt1    = (u16*)alloc((size_t)400*1024*2);
    u16*  Wt2    = (u16*)alloc((size_t)200*416*2);
    u16*  Wt3    = (u16*)alloc((size_t)400*256*2);
    u16*  Wt4    = (u16*)alloc((size_t)200*416*2);
    u16*  Wtc    = (u16*)alloc((size_t)100*448*2);
    u16*  g2     = h1;                              // N*32 elems, spans h1+g1 (contiguous)
    u16*  comb   = (u16*)ssrc;                      // 16384*432*2 = 13.5 MB <= 16 MB
    int*  rank   = (int*)h2;                        // 16 MB, dead before linear2 writes h2
    u16*  fp1    = h2;                              // 12.5 MB, after gather2
    u16*  tv1    = h2 + (size_t)N_GRAPH*400;        // next 12.5 MB

    (void)hipMemsetAsync(flagp, 0, 256, stream);
    (void)hipMemsetAsync(rowptr, 0, (size_t)(N+1)*4, stream);

    k_detect <<<1, 256, 0, stream>>>((const u32*)x, flagp);

    k_hist   <<<E/256, 256, 0, stream>>>(dstA, rowptr, rank, E);
    k_scan1  <<<512,   256, 0, stream>>>(rowptr, bsums);
    k_scan2  <<<1,     256, 0, stream>>>(bsums);
    k_scan3  <<<N/256, 256, 0, stream>>>(rowptr, bsums, N, E);
    k_scatter<<<E/256, 256, 0, stream>>>(srcA, dstA, rank, rowptr, ssrc, E);

    k_linear1<<<N/256, 256, 0, stream>>>(x, W1, as1w, ad1w, h1, ad1_, gkey1, flagp);
    k_gather1<<<N/256, 256, 0, stream>>>(rowptr, ssrc, h1, ad1_, gkey1, b1, g1, flagp);
    k_linear2<<<N/256, 256, 0, stream>>>(g1, W2, as2w, ad2w, h2, as2_, ad2_, gkey2, flagp);
    k_gather2<<<N/256, 256, 0, stream>>>(rowptr, ssrc, h2, as2_, ad2_, gkey2, b2, g2, flagp);
    k_pool   <<<N_GRAPH, 64, 0, stream>>>(g2, batch, comb, N);

    k_transpose<<<(400*1024+255)/256, 256, 0, stream>>>(fc1w, Wt1, 1024, 1024, 400, flagp);
    k_transpose<<<(200*416 +255)/256, 256, 0, stream>>>(fc2w, Wt2,  400,  416, 200, flagp);
    k_transpose<<<(400*256 +255)/256, 256, 0, stream>>>(fc3w, Wt3,  256,  256, 400, flagp);
    k_transpose<<<(200*416 +255)/256, 256, 0, stream>>>(fc4w, Wt4,  400,  416, 200, flagp);
    k_transpose<<<(100*448 +255)/256, 256, 0, stream>>>(fccw, Wtc,  432,  448, 100, flagp);

    k_gemm<<<dim3(128,4), 256, 0, stream>>>(fing, Wt1, fc1b, bn1, fp1, 1024, 1024, 400, 400,   0, 1, 1, 0, flagp);
    k_gemm<<<dim3(128,2), 256, 0, stream>>>(fp1,  Wt2, fc2b, bn2, comb, 400,  416, 200, 432,  32, 1, 0, 0, flagp);
    k_gemm<<<dim3(128,4), 256, 0, stream>>>(tv,   Wt3, fc3b, bn3, tv1,  256,  256, 400, 400,   0, 1, 1, 0, flagp);
    k_gemm<<<dim3(128,2), 256, 0, stream>>>(tv1,  Wt4, fc4b, bn4, comb, 400,  416, 200, 432, 232, 1, 0, 0, flagp);
    k_gemm<<<dim3(128,1), 256, 0, stream>>>(comb, Wtc, fccb, bnc, c1,   432,  448, 100, 100,   0, 1, 0, 1, flagp);

    k_fcc2<<<N_GRAPH/256, 256, 0, stream>>>(c1, fcc2w, fcc2b, (float*)d_out, flagp);
}

// Round 6
// 780.680 us; speedup vs baseline: 1.4634x; 1.3115x over previous
//
#include <hip/hip_runtime.h>

typedef unsigned short u16;
typedef unsigned int u32;
typedef __attribute__((ext_vector_type(8))) short bf16x8;
typedef __attribute__((ext_vector_type(4))) float f32x4;

#define N_NODES 524288
#define N_EDGES 4194304
#define N_GRAPH 16384
#define P_BLOCKS 1024          // P1/P2 blocks; 4096 edges each
#define BKTS 512               // coarse buckets = dst>>10
#define DPB 1024               // dsts per bucket
#define CAP 8960               // max edges per bucket (lambda=8192, +8.5 sigma)

__device__ __forceinline__ float bf2f(u16 u){ u32 x=((u32)u)<<16; float f; __builtin_memcpy(&f,&x,4); return f; }
__device__ __forceinline__ float lo2f(u32 u){ u32 x=u<<16; float f; __builtin_memcpy(&f,&x,4); return f; }
__device__ __forceinline__ float hi2f(u32 u){ u32 x=u&0xffff0000u; float f; __builtin_memcpy(&f,&x,4); return f; }
__device__ __forceinline__ u16 f2bf(float f){ u32 x; __builtin_memcpy(&x,&f,4); return (u16)((x + 0x7fffu + ((x>>16)&1u))>>16); }
__device__ __forceinline__ float lrelu(float e){ return e>0.f? e : 0.2f*e; }
__device__ __forceinline__ float gload(const void* p, int i, int is32){
    return is32 ? ((const float*)p)[i] : bf2f(((const u16*)p)[i]);
}
__device__ __forceinline__ u32 fmax_key(float f){ u32 u; __builtin_memcpy(&u,&f,4); return (u>>31)? ~u : (u|0x80000000u); }
__device__ __forceinline__ float key_fmax(u32 k){ u32 u = (k>>31)? (k^0x80000000u) : ~k; float f; __builtin_memcpy(&f,&u,4); return f; }

// ---------------- input dtype detector ----------------
__global__ __launch_bounds__(256) void k_detect(const u32* __restrict__ x, int* __restrict__ flag){
    __shared__ int cnt;
    if (threadIdx.x==0) cnt = 0;
    __syncthreads();
    int c = 0;
    for (int i = threadIdx.x; i < 1024; i += 256){
        u32 e = (x[i] >> 7) & 0xFF;
        if (e >= 110 && e <= 140) c++;
    }
    atomicAdd(&cnt, c);
    __syncthreads();
    if (threadIdx.x==0) *flag = (cnt < 512) ? 1 : 0;   // 1 = fp32 inputs
}

// ---------------- CSR build: bucketed counting sort (LDS atomics only) ----------------
// P1: per-block coarse histogram -> tbl_bm[blk*BKTS + bkt]  (coalesced)
__global__ __launch_bounds__(256) void k_p1(const int* __restrict__ dst, u32* __restrict__ tbl_bm){
    __shared__ u32 lh[BKTS];
    int t = threadIdx.x, blk = blockIdx.x;
    lh[t] = 0; lh[t+256] = 0;
    __syncthreads();
    int base = blk*4096;
    #pragma unroll
    for (int k=0;k<16;k++){
        int d = __builtin_nontemporal_load(dst + base + k*256 + t) & (N_NODES-1);
        atomicAdd(&lh[d>>10], 1);
    }
    __syncthreads();
    tbl_bm[blk*BKTS + t]       = lh[t];
    tbl_bm[blk*BKTS + t + 256] = lh[t+256];
}

// transpose tbl_bm (P_BLOCKS x BKTS) -> tbl_km (BKTS x P_BLOCKS)
__global__ __launch_bounds__(256) void k_ttbl(const u32* __restrict__ bm, u32* __restrict__ km){
    __shared__ u32 tile[32][33];
    int bx = blockIdx.x;        // blk tile (32 tiles)
    int by = blockIdx.y;        // bkt tile (16 tiles)
    int tx = threadIdx.x & 31, ty = threadIdx.x >> 5;   // 32 x 8
    #pragma unroll
    for (int r=0;r<32;r+=8)
        tile[ty+r][tx] = bm[(bx*32 + ty + r)*BKTS + by*32 + tx];
    __syncthreads();
    #pragma unroll
    for (int r=0;r<32;r+=8)
        km[(by*32 + ty + r)*P_BLOCKS + bx*32 + tx] = tile[tx][ty+r];
}

__global__ __launch_bounds__(256) void k_scan1(int* __restrict__ data, int* __restrict__ bsums){
    __shared__ int sh[256];
    int b = blockIdx.x, t = threadIdx.x;
    int base = b*1024 + t*4;
    int4 v = *(const int4*)(data + base);
    int s = v.x+v.y+v.z+v.w;
    sh[t] = s; __syncthreads();
    for (int off=1; off<256; off<<=1){
        int xv = (t>=off)? sh[t-off] : 0; __syncthreads();
        sh[t] += xv; __syncthreads();
    }
    int excl = sh[t] - s;
    if (t==255) bsums[b] = sh[255];
    int4 o; o.x = excl; o.y = excl+v.x; o.z = o.y+v.y; o.w = o.z+v.z;
    *(int4*)(data + base) = o;
}

__global__ __launch_bounds__(256) void k_scan2(int* __restrict__ bsums){ // 512 entries, 1 block
    __shared__ int sh[256];
    int t = threadIdx.x;
    int v0 = bsums[2*t], v1 = bsums[2*t+1];
    int s = v0+v1; sh[t] = s; __syncthreads();
    for (int off=1; off<256; off<<=1){
        int xv = (t>=off)? sh[t-off] : 0; __syncthreads();
        sh[t] += xv; __syncthreads();
    }
    int excl = sh[t] - s;
    bsums[2*t] = excl; bsums[2*t+1] = excl + v0;
}

__global__ __launch_bounds__(256) void k_scan3(int* __restrict__ scan, const int* __restrict__ bsums, int N_, int E_){
    int i = blockIdx.x*256 + threadIdx.x;
    if (i < N_) scan[i] += bsums[i>>10];
    if (i == 0) scan[N_] = E_;
}

// P2: scatter edges into bucket-major btab using LDS rank + LDS staging
__global__ __launch_bounds__(256) void k_p2(const int* __restrict__ src, const int* __restrict__ dst,
        const u32* __restrict__ km, u32* __restrict__ btab){
    __shared__ u32 lh[BKTS], lofs[BKTS], gofs[BKTS];
    __shared__ u32 stage[4096], tgt[4096];
    __shared__ u32 red[256];
    int t = threadIdx.x, blk = blockIdx.x;
    lh[t] = 0; lh[t+256] = 0;
    __syncthreads();
    u32 pr[16], rk[16]; u16 bk[16];
    int base = blk*4096;
    #pragma unroll
    for (int k=0;k<16;k++){
        int e = base + k*256 + t;
        int d = __builtin_nontemporal_load(dst+e) & (N_NODES-1);
        int s = __builtin_nontemporal_load(src+e) & (N_NODES-1);
        u32 b = (u32)d >> 10;
        bk[k] = (u16)b;
        pr[k] = (u32)(d & 1023) | ((u32)s << 10);
        rk[k] = atomicAdd(&lh[b], 1);
    }
    // preload this block's scanned global offsets (strided; table is L2-hot)
    gofs[t]       = km[(size_t)t*P_BLOCKS + blk];
    gofs[t+256]   = km[(size_t)(t+256)*P_BLOCKS + blk];
    __syncthreads();
    // exclusive scan of lh[512] -> lofs (2 entries/thread)
    u32 v0 = lh[2*t], v1 = lh[2*t+1];
    u32 s2 = v0+v1; red[t] = s2; __syncthreads();
    for (int off=1; off<256; off<<=1){
        u32 xv = (t>=off)? red[t-off] : 0; __syncthreads();
        red[t] += xv; __syncthreads();
    }
    u32 excl = red[t] - s2;
    lofs[2*t] = excl; lofs[2*t+1] = excl + v0;
    __syncthreads();
    #pragma unroll
    for (int k=0;k<16;k++){
        u32 p = lofs[bk[k]] + rk[k];
        stage[p] = pr[k];
        tgt[p]   = gofs[bk[k]] + rk[k];
    }
    __syncthreads();
    #pragma unroll
    for (int k=0;k<16;k++){
        int j = k*256 + t;
        btab[tgt[j]] = stage[j];
    }
}

// P3: per-bucket fine sort -> rowptr slice + sorted ssrc (all coalesced global IO)
__global__ __launch_bounds__(256) void k_p3(const u32* __restrict__ km, const u32* __restrict__ btab,
        int* __restrict__ rowptr, int* __restrict__ ssrc){
    __shared__ u32 fh[DPB], fo[DPB];
    __shared__ u32 red[256];
    __shared__ int sst[CAP];
    int t = threadIdx.x, b = blockIdx.x;
    u32 basep = km[(size_t)b*P_BLOCKS];
    u32 endp  = km[(size_t)(b+1)*P_BLOCKS];   // sentinel km[BKTS*P_BLOCKS] = E
    int cnt = (int)(endp - basep);
    #pragma unroll
    for (int i=t;i<DPB;i+=256) fh[i] = 0;
    __syncthreads();
    for (int j=t; j<cnt; j+=256){
        u32 p = btab[basep + j];
        atomicAdd(&fh[p & 1023], 1);
    }
    __syncthreads();
    // exclusive scan of fh[1024] -> fo (4 entries/thread)
    u32 v0=fh[4*t], v1=fh[4*t+1], v2=fh[4*t+2], v3=fh[4*t+3];
    u32 s4 = v0+v1+v2+v3; red[t] = s4; __syncthreads();
    for (int off=1; off<256; off<<=1){
        u32 xv = (t>=off)? red[t-off] : 0; __syncthreads();
        red[t] += xv; __syncthreads();
    }
    u32 excl = red[t] - s4;
    fo[4*t]=excl; fo[4*t+1]=excl+v0; fo[4*t+2]=excl+v0+v1; fo[4*t+3]=excl+v0+v1+v2;
    __syncthreads();
    #pragma unroll
    for (int i=t;i<DPB;i+=256) rowptr[b*DPB + i] = (int)(basep + fo[i]);
    if (b == BKTS-1 && t == 0) rowptr[N_NODES] = (int)endp;
    __syncthreads();
    for (int j=t; j<cnt; j+=256){
        u32 p = btab[basep + j];
        u32 pos = atomicAdd(&fo[p & 1023], 1);
        if (pos < (u32)CAP) sst[pos] = (int)(p >> 10);
    }
    __syncthreads();
    for (int j=t; j<cnt; j+=256) ssrc[basep + j] = sst[j];
}

// ---------------- GAT node linears (also reduce global max of a_src score) ----------------
__global__ __launch_bounds__(256) void k_linear1(const void* __restrict__ x,
        const void* __restrict__ W1, const void* __restrict__ asw, const void* __restrict__ adw,
        u16* __restrict__ h1, float* __restrict__ ad1, u32* __restrict__ gkey,
        const int* __restrict__ flag){
    int is32 = *flag;
    __shared__ float Wf[196], av[14], dv[14];
    __shared__ float red[256];
    int t = threadIdx.x;
    if (t < 196) Wf[t] = gload(W1, t, is32);
    else if (t < 210) av[t-196] = gload(asw, t-196, is32);
    else if (t < 224) dv[t-210] = gload(adw, t-210, is32);
    __syncthreads();
    int i = blockIdx.x*256 + t;
    float xv[14];
    if (is32){
        const float* xr = (const float*)x + (size_t)i*14;
        #pragma unroll
        for (int k=0;k<14;k++) xv[k] = xr[k];
    } else {
        const u32* xr = (const u32*)((const u16*)x + (size_t)i*14);
        #pragma unroll
        for (int p=0;p<7;p++){ u32 u = xr[p]; xv[2*p]=lo2f(u); xv[2*p+1]=hi2f(u); }
    }
    float h[14];
    #pragma unroll
    for (int j=0;j<14;j++){ float s=0.f;
        #pragma unroll
        for (int k=0;k<14;k++) s += xv[k]*Wf[k*14+j];
        h[j]=s; }
    float a=0.f, d=0.f;
    #pragma unroll
    for (int j=0;j<14;j++){ a += h[j]*av[j]; d += h[j]*dv[j]; }
    ad1[i]=d;
    u32 ou[8];
    #pragma unroll
    for (int p=0;p<7;p++) ou[p] = (u32)f2bf(h[2*p]) | ((u32)f2bf(h[2*p+1])<<16);
    __builtin_memcpy(&ou[7], &a, 4);   // fp32 a_src score packed in slots 14..15
    uint4* hp = (uint4*)(h1 + (size_t)i*16);
    hp[0] = make_uint4(ou[0],ou[1],ou[2],ou[3]);
    hp[1] = make_uint4(ou[4],ou[5],ou[6],ou[7]);
    red[t] = a; __syncthreads();
    for (int o=128;o;o>>=1){ if (t<o) red[t]=fmaxf(red[t],red[t+o]); __syncthreads(); }
    if (t==0) atomicMax(gkey, fmax_key(red[0]));
}

__global__ __launch_bounds__(256) void k_linear2(const u16* __restrict__ g1,
        const void* __restrict__ W2, const void* __restrict__ asw, const void* __restrict__ adw,
        u16* __restrict__ h2, float* __restrict__ as2, float* __restrict__ ad2,
        u32* __restrict__ gkey, const int* __restrict__ flag){
    int is32 = *flag;
    __shared__ float Wf[448], av[32], dv[32];
    __shared__ float red[256];
    int t = threadIdx.x;
    for (int idx=t; idx<448; idx+=256) Wf[idx] = gload(W2, idx, is32);
    if (t < 32) { av[t] = gload(asw, t, is32); dv[t] = gload(adw, t, is32); }
    __syncthreads();
    int i = blockIdx.x*256 + t;
    const uint4* gp = (const uint4*)(g1 + (size_t)i*16);
    uint4 q0 = gp[0], q1 = gp[1];
    u32 u[8] = {q0.x,q0.y,q0.z,q0.w,q1.x,q1.y,q1.z,q1.w};
    float gv[14];
    #pragma unroll
    for (int k=0;k<14;k++){ u32 uu=u[k>>1]; gv[k] = (k&1)? hi2f(uu) : lo2f(uu); }
    float h[32];
    #pragma unroll
    for (int j=0;j<32;j++) h[j]=0.f;
    #pragma unroll
    for (int k=0;k<14;k++){ float g_ = gv[k];
        #pragma unroll
        for (int j=0;j<32;j++) h[j] += g_*Wf[k*32+j]; }
    float a=0.f, d=0.f;
    #pragma unroll
    for (int j=0;j<32;j++){ a += h[j]*av[j]; d += h[j]*dv[j]; }
    as2[i]=a; ad2[i]=d;
    u32 ou[16];
    #pragma unroll
    for (int p=0;p<16;p++) ou[p] = (u32)f2bf(h[2*p]) | ((u32)f2bf(h[2*p+1])<<16);
    uint4* hp = (uint4*)(h2 + (size_t)i*32);
    hp[0]=make_uint4(ou[0],ou[1],ou[2],ou[3]);
    hp[1]=make_uint4(ou[4],ou[5],ou[6],ou[7]);
    hp[2]=make_uint4(ou[8],ou[9],ou[10],ou[11]);
    hp[3]=make_uint4(ou[12],ou[13],ou[14],ou[15]);
    red[t] = a; __syncthreads();
    for (int o=128;o;o>>=1){ if (t<o) red[t]=fmaxf(red[t],red[t+o]); __syncthreads(); }
    if (t==0) atomicMax(gkey, fmax_key(red[0]));
}

// ---------------- GAT gather: single pass, global-max-bound softmax ----------------
__global__ __launch_bounds__(256) void k_gather1(const int* __restrict__ rowptr, const int* __restrict__ ssrc,
        const u16* __restrict__ h1, const float* __restrict__ ad1, const u32* __restrict__ gkey,
        const void* __restrict__ b1, u16* __restrict__ g1, const int* __restrict__ flag){
    int is32 = *flag;
    int i = blockIdx.x*256 + threadIdx.x;
    float adv = ad1[i];
    float M = lrelu(key_fmax(*gkey) + adv);
    int beg = rowptr[i], end = rowptr[i+1];
    float acc[14], den;
    {
        const uint4* hp = (const uint4*)(h1 + (size_t)i*16);
        uint4 q0=hp[0], q1=hp[1];
        float as_; __builtin_memcpy(&as_, &q1.w, 4);
        float w = __expf(lrelu(as_ + adv) - M); den = w;
        u32 u[7] = {q0.x,q0.y,q0.z,q0.w,q1.x,q1.y,q1.z};
        #pragma unroll
        for (int f=0;f<14;f++){ u32 uu=u[f>>1]; acc[f] = w*((f&1)? hi2f(uu):lo2f(uu)); }
    }
    for (int j=beg; j<end; j++){
        int s = __builtin_nontemporal_load(ssrc+j);
        const uint4* hp = (const uint4*)(h1 + (size_t)s*16);
        uint4 q0=hp[0], q1=hp[1];
        float as_; __builtin_memcpy(&as_, &q1.w, 4);
        float w = __expf(lrelu(as_ + adv) - M); den += w;
        u32 u[7] = {q0.x,q0.y,q0.z,q0.w,q1.x,q1.y,q1.z};
        #pragma unroll
        for (int f=0;f<14;f++){ u32 uu=u[f>>1]; acc[f] += w*((f&1)? hi2f(uu):lo2f(uu)); }
    }
    float inv = 1.0f/den;
    u32 ou[8];
    #pragma unroll
    for (int p=0;p<7;p++){
        float v0 = fmaxf(acc[2*p]*inv + gload(b1,2*p,is32), 0.f);
        float v1 = fmaxf(acc[2*p+1]*inv + gload(b1,2*p+1,is32), 0.f);
        ou[p] = (u32)f2bf(v0) | ((u32)f2bf(v1)<<16);
    }
    ou[7]=0u;
    uint4* gp = (uint4*)(g1 + (size_t)i*16);
    gp[0]=make_uint4(ou[0],ou[1],ou[2],ou[3]);
    gp[1]=make_uint4(ou[4],ou[5],ou[6],ou[7]);
}

__global__ __launch_bounds__(256) void k_gather2(const int* __restrict__ rowptr, const int* __restrict__ ssrc,
        const u16* __restrict__ h2, const float* __restrict__ as2, const float* __restrict__ ad2,
        const u32* __restrict__ gkey, const void* __restrict__ b2, u16* __restrict__ g2,
        const int* __restrict__ flag){
    int is32 = *flag;
    int i = blockIdx.x*256 + threadIdx.x;
    float adv = ad2[i];
    float M = lrelu(key_fmax(*gkey) + adv);
    int beg = rowptr[i], end = rowptr[i+1];
    float acc[32], den;
    {
        float w = __expf(lrelu(as2[i] + adv) - M); den = w;
        const uint4* hp = (const uint4*)(h2 + (size_t)i*32);
        uint4 q0=hp[0], q1=hp[1], q2=hp[2], q3=hp[3];
        u32 u[16] = {q0.x,q0.y,q0.z,q0.w,q1.x,q1.y,q1.z,q1.w,q2.x,q2.y,q2.z,q2.w,q3.x,q3.y,q3.z,q3.w};
        #pragma unroll
        for (int f=0;f<32;f++){ u32 uu=u[f>>1]; acc[f] = w*((f&1)? hi2f(uu):lo2f(uu)); }
    }
    for (int j=beg; j<end; j++){
        int s = __builtin_nontemporal_load(ssrc+j);
        float w = __expf(lrelu(as2[s] + adv) - M); den += w;
        const uint4* hp = (const uint4*)(h2 + (size_t)s*32);
        uint4 q0=hp[0], q1=hp[1], q2=hp[2], q3=hp[3];
        u32 u[16] = {q0.x,q0.y,q0.z,q0.w,q1.x,q1.y,q1.z,q1.w,q2.x,q2.y,q2.z,q2.w,q3.x,q3.y,q3.z,q3.w};
        #pragma unroll
        for (int f=0;f<32;f++){ u32 uu=u[f>>1]; acc[f] += w*((f&1)? hi2f(uu):lo2f(uu)); }
    }
    float inv = 1.0f/den;
    u32 ou[16];
    #pragma unroll
    for (int p=0;p<16;p++){
        float v0 = fmaxf(acc[2*p]*inv + gload(b2,2*p,is32), 0.f);
        float v1 = fmaxf(acc[2*p+1]*inv + gload(b2,2*p+1,is32), 0.f);
        ou[p] = (u32)f2bf(v0) | ((u32)f2bf(v1)<<16);
    }
    uint4* gp = (uint4*)(g2 + (size_t)i*32);
    gp[0]=make_uint4(ou[0],ou[1],ou[2],ou[3]);
    gp[1]=make_uint4(ou[4],ou[5],ou[6],ou[7]);
    gp[2]=make_uint4(ou[8],ou[9],ou[10],ou[11]);
    gp[3]=make_uint4(ou[12],ou[13],ou[14],ou[15]);
}

// ---------------- pool (batch is sorted; binary search per graph) ----------------
__device__ __forceinline__ int lbound(const int* __restrict__ a, int n, int v){
    int lo=0, hi=n;
    while (lo < hi){ int m = (lo+hi)>>1; if (a[m] < v) lo = m+1; else hi = m; }
    return lo;
}

__global__ __launch_bounds__(64) void k_pool(const u16* __restrict__ g2, const int* __restrict__ batch,
        u16* __restrict__ comb, int N_){
    int b = blockIdx.x;
    int t = threadIdx.x, f = t & 31, half = t >> 5;
    int lo = lbound(batch, N_, b);
    int hi = lbound(batch, N_, b+1);
    float acc = 0.f;
    for (int i = lo + half; i < hi; i += 2) acc += bf2f(g2[(size_t)i*32 + f]);
    acc += __shfl_xor(acc, 32);
    if (t < 32) comb[(size_t)b*432 + f] = f2bf(acc);
}

// ---------------- weight transpose (W[KxN] -> Wt[N x Kp] bf16, zero-pad K..Kp) ----------------
__global__ __launch_bounds__(256) void k_transpose(const void* __restrict__ W, u16* __restrict__ Wt,
        int K, int Kp, int Nc, const int* __restrict__ flag){
    int is32 = *flag;
    int idx = blockIdx.x*256 + threadIdx.x;
    if (idx >= Nc*Kp) return;
    int n = idx / Kp, k = idx - n*Kp;
    Wt[idx] = (k < K) ? f2bf(gload(W, k*Nc + n, is32)) : (u16)0;
}

// ---------------- fused GEMM + bias + BN + ReLU (bf16 MFMA, 128x128 tile) ----------------
__global__ __launch_bounds__(256) void k_gemm(const void* __restrict__ A, const u16* __restrict__ Wt,
        const void* __restrict__ bias, const void* __restrict__ bnp, void* __restrict__ out,
        int K, int Kp, int Nc, int ostride, int ooff, int do_relu,
        int afollow, int out32, const int* __restrict__ flag){
    int is32 = *flag;
    int a32 = afollow ? is32 : 0;
    __shared__ u16 As[128][40];
    __shared__ u16 Bs[128][40];
    int t = threadIdx.x;
    int lane = t & 63, wave = t >> 6;
    int bm = blockIdx.x * 128;
    int bn = blockIdx.y * 128;
    int mt = (wave & 1) * 64, nt = (wave >> 1) * 64;
    int quad = lane >> 4, fr = lane & 15;

    f32x4 zero = {0.f, 0.f, 0.f, 0.f};
    f32x4 acc[4][4];
    #pragma unroll
    for (int i=0;i<4;i++)
        #pragma unroll
        for (int j=0;j<4;j++) acc[i][j] = zero;

    int srow0 = t >> 2;          // 0..63
    int scol = (t & 3) * 8;      // 0,8,16,24

    for (int k0 = 0; k0 < Kp; k0 += 32){
        #pragma unroll
        for (int h2_=0; h2_<2; h2_++){
            int row = srow0 + h2_*64;
            int gk = k0 + scol;
            if (a32){
                float4 a0 = {0,0,0,0}, a1 = {0,0,0,0};
                if (gk + 8 <= K){
                    const float* ap = (const float*)A + (size_t)(bm+row)*K + gk;
                    a0 = *(const float4*)ap; a1 = *(const float4*)(ap+4);
                }
                u32 w0 = (u32)f2bf(a0.x) | ((u32)f2bf(a0.y)<<16);
                u32 w1 = (u32)f2bf(a0.z) | ((u32)f2bf(a0.w)<<16);
                u32 w2 = (u32)f2bf(a1.x) | ((u32)f2bf(a1.y)<<16);
                u32 w3 = (u32)f2bf(a1.z) | ((u32)f2bf(a1.w)<<16);
                *(uint4*)(&As[row][scol]) = make_uint4(w0,w1,w2,w3);
            } else {
                uint4 av = make_uint4(0,0,0,0);
                if (gk + 8 <= K) av = *(const uint4*)((const u16*)A + (size_t)(bm+row)*K + gk);
                *(uint4*)(&As[row][scol]) = av;
            }
            uint4 bv = make_uint4(0,0,0,0);
            if (bn + row < Nc) bv = *(const uint4*)(Wt + (size_t)(bn+row)*Kp + gk);
            *(uint4*)(&Bs[row][scol]) = bv;
        }
        __syncthreads();
        bf16x8 af[4], bfr[4];
        #pragma unroll
        for (int i=0;i<4;i++) af[i] = *(const bf16x8*)(&As[mt + i*16 + fr][quad*8]);
        #pragma unroll
        for (int j=0;j<4;j++) bfr[j] = *(const bf16x8*)(&Bs[nt + j*16 + fr][quad*8]);
        #pragma unroll
        for (int i=0;i<4;i++)
            #pragma unroll
            for (int j=0;j<4;j++)
                acc[i][j] = __builtin_amdgcn_mfma_f32_16x16x32_bf16(af[i], bfr[j], acc[i][j], 0, 0, 0);
        __syncthreads();
    }

    #pragma unroll
    for (int j=0;j<4;j++){
        int gn = bn + nt + j*16 + fr;
        if (gn >= Nc) continue;
        float bb = gload(bias, gn, is32);
        float scale = 1.f, shift = bb;
        if (bnp){
            float gm_ = gload(bnp, gn, is32), bt = gload(bnp, Nc+gn, is32);
            float mn = gload(bnp, 2*Nc+gn, is32), vr = gload(bnp, 3*Nc+gn, is32);
            scale = gm_ * rsqrtf(vr + 1e-5f);
            shift = (bb - mn)*scale + bt;
        }
        #pragma unroll
        for (int i=0;i<4;i++){
            #pragma unroll
            for (int r=0;r<4;r++){
                int gm = bm + mt + i*16 + quad*4 + r;
                float v = acc[i][j][r]*scale + shift;
                if (do_relu) v = fmaxf(v, 0.f);
                size_t oidx = (size_t)gm*ostride + ooff + gn;
                if (out32) ((float*)out)[oidx] = v;
                else       ((u16*)out)[oidx] = f2bf(v);
            }
        }
    }
}

// ---------------- final fcc2 (K=100, Nc=1) -> FP32 output ----------------
__global__ __launch_bounds__(256) void k_fcc2(const float* __restrict__ c1, const void* __restrict__ w,
        const void* __restrict__ b, float* __restrict__ outp, const int* __restrict__ flag){
    int is32 = *flag;
    __shared__ float wf[100];
    int t = threadIdx.x;
    if (t < 100) wf[t] = gload(w, t, is32);
    __syncthreads();
    int i = blockIdx.x*256 + t;
    const float* r = c1 + (size_t)i*100;
    float s = 0.f;
    #pragma unroll 4
    for (int k=0;k<100;k++) s += r[k]*wf[k];
    outp[i] = s + gload(b, 0, is32);
}

extern "C" void kernel_launch(void* const* d_in, const int* in_sizes, int n_in,
                              void* d_out, int out_size, void* d_ws, size_t ws_size,
                              hipStream_t stream){
    const int N = N_NODES, E = N_EDGES;
    const void* x    = d_in[0];
    const int* ei   = (const int*)d_in[1];
    const int* srcA = ei;
    const int* dstA = ei + E;
    const int* batch= (const int*)d_in[2];
    const void* fing = d_in[3];
    const void* tv   = d_in[4];
    const void* W1   = d_in[5];
    const void* as1w = d_in[6];
    const void* ad1w = d_in[7];
    const void* b1   = d_in[8];
    const void* W2   = d_in[9];
    const void* as2w = d_in[10];
    const void* ad2w = d_in[11];
    const void* b2   = d_in[12];
    const void* fc1w = d_in[13]; const void* fc1b = d_in[14]; const void* bn1 = d_in[15];
    const void* fc2w = d_in[16]; const void* fc2b = d_in[17]; const void* bn2 = d_in[18];
    const void* fc3w = d_in[19]; const void* fc3b = d_in[20]; const void* bn3 = d_in[21];
    const void* fc4w = d_in[22]; const void* fc4b = d_in[23]; const void* bn4 = d_in[24];
    const void* fccw = d_in[25]; const void* fccb = d_in[26]; const void* bnc = d_in[27];
    const void* fcc2w= d_in[28]; const void* fcc2b= d_in[29];

    char* ws = (char*)d_ws;
    size_t off = 0;
    auto alloc = [&](size_t bytes)->char*{ char* p = ws + off; off = (off + bytes + 255) & ~(size_t)255; return p; };
    int*  flagp  = (int*)alloc(256);          // [0]=dtype flag; [1]=gkey1; [2]=gkey2
    u32*  gkey1  = (u32*)flagp + 1;
    u32*  gkey2  = (u32*)flagp + 2;
    int*  rowptr = (int*)alloc((size_t)(N+1)*4);
    int*  bsums  = (int*)alloc(513*4);
    u32*  tbl_bm = (u32*)alloc((size_t)BKTS*P_BLOCKS*4);
    u32*  tbl_km = (u32*)alloc(((size_t)BKTS*P_BLOCKS+1)*4);
    int*  ssrc   = (int*)alloc((size_t)E*4);       // 16 MB; comb aliases after gathers
    u16*  h1     = (u16*)alloc((size_t)N*16*2);    // g2 aliases [h1|g1]
    u16*  g1     = (u16*)alloc((size_t)N*16*2);
    float* ad1_  = (float*)alloc((size_t)N*4);
    float* as2_  = (float*)alloc((size_t)N*4);
    float* ad2_  = (float*)alloc((size_t)N*4);
    u16*  h2     = (u16*)alloc((size_t)N*32*2);    // 32 MB; btab + fp1/tv1 alias
    float* c1    = (float*)alloc((size_t)N_GRAPH*100*4);
    u16*  Wt1    = (u16*)alloc((size_t)400*1024*2);
    u16*  Wt2    = (u16*)alloc((size_t)200*416*2);
    u16*  Wt3    = (u16*)alloc((size_t)400*256*2);
    u16*  Wt4    = (u16*)alloc((size_t)200*416*2);
    u16*  Wtc    = (u16*)alloc((size_t)100*448*2);
    u16*  g2     = h1;                              // N*32 elems, spans h1+g1 (contiguous)
    u16*  comb   = (u16*)ssrc;                      // 16384*432*2 = 13.5 MB <= 16 MB
    u32*  btab   = (u32*)h2;                        // 16 MB, dead before linear2 writes h2
    u16*  fp1    = h2;                              // 12.5 MB, after gather2
    u16*  tv1    = h2 + (size_t)N_GRAPH*400;        // next 12.5 MB

    (void)hipMemsetAsync(flagp, 0, 256, stream);

    k_detect <<<1, 256, 0, stream>>>((const u32*)x, flagp);

    // CSR build: bucketed counting sort, no global atomics
    k_p1   <<<P_BLOCKS, 256, 0, stream>>>(dstA, tbl_bm);
    k_ttbl <<<dim3(32,16), 256, 0, stream>>>(tbl_bm, tbl_km);
    k_scan1<<<512,  256, 0, stream>>>((int*)tbl_km, bsums);
    k_scan2<<<1,    256, 0, stream>>>(bsums);
    k_scan3<<<(BKTS*P_BLOCKS)/256, 256, 0, stream>>>((int*)tbl_km, bsums, BKTS*P_BLOCKS, E);
    k_p2   <<<P_BLOCKS, 256, 0, stream>>>(srcA, dstA, tbl_km, btab);
    k_p3   <<<BKTS, 256, 0, stream>>>(tbl_km, btab, rowptr, ssrc);

    k_linear1<<<N/256, 256, 0, stream>>>(x, W1, as1w, ad1w, h1, ad1_, gkey1, flagp);
    k_gather1<<<N/256, 256, 0, stream>>>(rowptr, ssrc, h1, ad1_, gkey1, b1, g1, flagp);
    k_linear2<<<N/256, 256, 0, stream>>>(g1, W2, as2w, ad2w, h2, as2_, ad2_, gkey2, flagp);
    k_gather2<<<N/256, 256, 0, stream>>>(rowptr, ssrc, h2, as2_, ad2_, gkey2, b2, g2, flagp);
    k_pool   <<<N_GRAPH, 64, 0, stream>>>(g2, batch, comb, N);

    k_transpose<<<(400*1024+255)/256, 256, 0, stream>>>(fc1w, Wt1, 1024, 1024, 400, flagp);
    k_transpose<<<(200*416 +255)/256, 256, 0, stream>>>(fc2w, Wt2,  400,  416, 200, flagp);
    k_transpose<<<(400*256 +255)/256, 256, 0, stream>>>(fc3w, Wt3,  256,  256, 400, flagp);
    k_transpose<<<(200*416 +255)/256, 256, 0, stream>>>(fc4w, Wt4,  400,  416, 200, flagp);
    k_transpose<<<(100*448 +255)/256, 256, 0, stream>>>(fccw, Wtc,  432,  448, 100, flagp);

    k_gemm<<<dim3(128,4), 256, 0, stream>>>(fing, Wt1, fc1b, bn1, fp1, 1024, 1024, 400, 400,   0, 1, 1, 0, flagp);
    k_gemm<<<dim3(128,2), 256, 0, stream>>>(fp1,  Wt2, fc2b, bn2, comb, 400,  416, 200, 432,  32, 1, 0, 0, flagp);
    k_gemm<<<dim3(128,4), 256, 0, stream>>>(tv,   Wt3, fc3b, bn3, tv1,  256,  256, 400, 400,   0, 1, 1, 0, flagp);
    k_gemm<<<dim3(128,2), 256, 0, stream>>>(tv1,  Wt4, fc4b, bn4, comb, 400,  416, 200, 432, 232, 1, 0, 0, flagp);
    k_gemm<<<dim3(128,1), 256, 0, stream>>>(comb, Wtc, fccb, bnc, c1,   432,  448, 100, 100,   0, 1, 0, 1, flagp);

    k_fcc2<<<N_GRAPH/256, 256, 0, stream>>>(c1, fcc2w, fcc2b, (float*)d_out, flagp);
}

// Round 7
// 729.976 us; speedup vs baseline: 1.5650x; 1.0695x over previous
//
#include <hip/hip_runtime.h>

typedef unsigned short u16;
typedef unsigned int u32;
typedef __attribute__((ext_vector_type(8))) short bf16x8;
typedef __attribute__((ext_vector_type(4))) float f32x4;

#define N_NODES 524288
#define N_EDGES 4194304
#define N_GRAPH 16384
#define P_BLOCKS 1024          // P1/P2 blocks; 4096 edges each
#define BKTS 512               // coarse buckets = dst>>10
#define DPB 1024               // dsts per bucket
#define CAP 8960               // max edges per bucket

__device__ __forceinline__ float bf2f(u16 u){ u32 x=((u32)u)<<16; float f; __builtin_memcpy(&f,&x,4); return f; }
__device__ __forceinline__ float lo2f(u32 u){ u32 x=u<<16; float f; __builtin_memcpy(&f,&x,4); return f; }
__device__ __forceinline__ float hi2f(u32 u){ u32 x=u&0xffff0000u; float f; __builtin_memcpy(&f,&x,4); return f; }
__device__ __forceinline__ u16 f2bf(float f){ u32 x; __builtin_memcpy(&x,&f,4); return (u16)((x + 0x7fffu + ((x>>16)&1u))>>16); }
__device__ __forceinline__ float lrelu(float e){ return e>0.f? e : 0.2f*e; }
__device__ __forceinline__ float gload(const void* p, int i, int is32){
    return is32 ? ((const float*)p)[i] : bf2f(((const u16*)p)[i]);
}
__device__ __forceinline__ u32 fmax_key(float f){ u32 u; __builtin_memcpy(&u,&f,4); return (u>>31)? ~u : (u|0x80000000u); }
__device__ __forceinline__ float key_fmax(u32 k){ u32 u = (k>>31)? (k^0x80000000u) : ~k; float f; __builtin_memcpy(&f,&u,4); return f; }

// accumulate one edge given its 32B row (14 bf16 + fp32 score in q1.w)
__device__ __forceinline__ void edge_acc(uint4 q0, uint4 q1, float adv, float M,
        float* acc, float& den){
    float as_; __builtin_memcpy(&as_, &q1.w, 4);
    float w = __expf(lrelu(as_ + adv) - M); den += w;
    u32 u[7] = {q0.x,q0.y,q0.z,q0.w,q1.x,q1.y,q1.z};
    #pragma unroll
    for (int f=0;f<14;f++){ u32 uu=u[f>>1]; acc[f] += w*((f&1)? hi2f(uu):lo2f(uu)); }
}

// ---------------- input dtype detector ----------------
__global__ __launch_bounds__(256) void k_detect(const u32* __restrict__ x, int* __restrict__ flag){
    __shared__ int cnt;
    if (threadIdx.x==0) cnt = 0;
    __syncthreads();
    int c = 0;
    for (int i = threadIdx.x; i < 1024; i += 256){
        u32 e = (x[i] >> 7) & 0xFF;
        if (e >= 110 && e <= 140) c++;
    }
    atomicAdd(&cnt, c);
    __syncthreads();
    if (threadIdx.x==0) *flag = (cnt < 512) ? 1 : 0;   // 1 = fp32 inputs
}

// ---------------- prep: va = W2 @ a_s2, vd = W2 @ a_d2 (14 each) ----------------
__global__ __launch_bounds__(64) void k_prep(const void* __restrict__ W2, const void* __restrict__ asw,
        const void* __restrict__ adw, float* __restrict__ prep, const int* __restrict__ flag){
    int is32 = *flag;
    int t = threadIdx.x;
    if (t < 28){
        int j = t % 14, which = t / 14;
        const void* av = which ? adw : asw;
        float s = 0.f;
        #pragma unroll
        for (int k=0;k<32;k++) s += gload(W2, j*32+k, is32) * gload(av, k, is32);
        prep[which*14 + j] = s;
    }
}

// ---------------- fp32->bf16 cast (8 elems/thread) ----------------
__global__ __launch_bounds__(256) void k_cast(const void* __restrict__ in, u16* __restrict__ out,
        int n8, const int* __restrict__ flag){
    int is32 = *flag;
    int idx = blockIdx.x*256 + threadIdx.x;
    if (idx >= n8) return;
    if (is32){
        const float4* ip = (const float4*)in + idx*2;
        float4 a0 = ip[0], a1 = ip[1];
        u32 w0 = (u32)f2bf(a0.x) | ((u32)f2bf(a0.y)<<16);
        u32 w1 = (u32)f2bf(a0.z) | ((u32)f2bf(a0.w)<<16);
        u32 w2 = (u32)f2bf(a1.x) | ((u32)f2bf(a1.y)<<16);
        u32 w3 = (u32)f2bf(a1.z) | ((u32)f2bf(a1.w)<<16);
        ((uint4*)out)[idx] = make_uint4(w0,w1,w2,w3);
    } else {
        ((uint4*)out)[idx] = ((const uint4*)in)[idx];
    }
}

// ---------------- CSR build: bucketed counting sort (LDS atomics only) ----------------
__global__ __launch_bounds__(256) void k_p1(const int* __restrict__ dst, u32* __restrict__ tbl_bm){
    __shared__ u32 lh[BKTS];
    int t = threadIdx.x, blk = blockIdx.x;
    lh[t] = 0; lh[t+256] = 0;
    __syncthreads();
    int base = blk*4096;
    #pragma unroll
    for (int k=0;k<16;k++){
        int d = __builtin_nontemporal_load(dst + base + k*256 + t) & (N_NODES-1);
        atomicAdd(&lh[d>>10], 1);
    }
    __syncthreads();
    tbl_bm[blk*BKTS + t]       = lh[t];
    tbl_bm[blk*BKTS + t + 256] = lh[t+256];
}

__global__ __launch_bounds__(256) void k_ttbl(const u32* __restrict__ bm, u32* __restrict__ km){
    __shared__ u32 tile[32][33];
    int bx = blockIdx.x, by = blockIdx.y;
    int tx = threadIdx.x & 31, ty = threadIdx.x >> 5;
    #pragma unroll
    for (int r=0;r<32;r+=8)
        tile[ty+r][tx] = bm[(bx*32 + ty + r)*BKTS + by*32 + tx];
    __syncthreads();
    #pragma unroll
    for (int r=0;r<32;r+=8)
        km[(by*32 + ty + r)*P_BLOCKS + bx*32 + tx] = tile[tx][ty+r];
}

__global__ __launch_bounds__(256) void k_scan1(int* __restrict__ data, int* __restrict__ bsums){
    __shared__ int sh[256];
    int b = blockIdx.x, t = threadIdx.x;
    int base = b*1024 + t*4;
    int4 v = *(const int4*)(data + base);
    int s = v.x+v.y+v.z+v.w;
    sh[t] = s; __syncthreads();
    for (int off=1; off<256; off<<=1){
        int xv = (t>=off)? sh[t-off] : 0; __syncthreads();
        sh[t] += xv; __syncthreads();
    }
    int excl = sh[t] - s;
    if (t==255) bsums[b] = sh[255];
    int4 o; o.x = excl; o.y = excl+v.x; o.z = o.y+v.y; o.w = o.z+v.z;
    *(int4*)(data + base) = o;
}

__global__ __launch_bounds__(256) void k_scan2(int* __restrict__ bsums){
    __shared__ int sh[256];
    int t = threadIdx.x;
    int v0 = bsums[2*t], v1 = bsums[2*t+1];
    int s = v0+v1; sh[t] = s; __syncthreads();
    for (int off=1; off<256; off<<=1){
        int xv = (t>=off)? sh[t-off] : 0; __syncthreads();
        sh[t] += xv; __syncthreads();
    }
    int excl = sh[t] - s;
    bsums[2*t] = excl; bsums[2*t+1] = excl + v0;
}

__global__ __launch_bounds__(256) void k_scan3(int* __restrict__ scan, const int* __restrict__ bsums, int N_, int E_){
    int i = blockIdx.x*256 + threadIdx.x;
    if (i < N_) scan[i] += bsums[i>>10];
    if (i == 0) scan[N_] = E_;
}

__global__ __launch_bounds__(256) void k_p2(const int* __restrict__ src, const int* __restrict__ dst,
        const u32* __restrict__ km, u32* __restrict__ btab){
    __shared__ u32 lh[BKTS], lofs[BKTS], gofs[BKTS];
    __shared__ u32 stage[4096], tgt[4096];
    __shared__ u32 red[256];
    int t = threadIdx.x, blk = blockIdx.x;
    lh[t] = 0; lh[t+256] = 0;
    __syncthreads();
    u32 pr[16], rk[16]; u16 bk[16];
    int base = blk*4096;
    #pragma unroll
    for (int k=0;k<16;k++){
        int e = base + k*256 + t;
        int d = __builtin_nontemporal_load(dst+e) & (N_NODES-1);
        int s = __builtin_nontemporal_load(src+e) & (N_NODES-1);
        u32 b = (u32)d >> 10;
        bk[k] = (u16)b;
        pr[k] = (u32)(d & 1023) | ((u32)s << 10);
        rk[k] = atomicAdd(&lh[b], 1);
    }
    gofs[t]       = km[(size_t)t*P_BLOCKS + blk];
    gofs[t+256]   = km[(size_t)(t+256)*P_BLOCKS + blk];
    __syncthreads();
    u32 v0 = lh[2*t], v1 = lh[2*t+1];
    u32 s2 = v0+v1; red[t] = s2; __syncthreads();
    for (int off=1; off<256; off<<=1){
        u32 xv = (t>=off)? red[t-off] : 0; __syncthreads();
        red[t] += xv; __syncthreads();
    }
    u32 excl = red[t] - s2;
    lofs[2*t] = excl; lofs[2*t+1] = excl + v0;
    __syncthreads();
    #pragma unroll
    for (int k=0;k<16;k++){
        u32 p = lofs[bk[k]] + rk[k];
        stage[p] = pr[k];
        tgt[p]   = gofs[bk[k]] + rk[k];
    }
    __syncthreads();
    #pragma unroll
    for (int k=0;k<16;k++){
        int j = k*256 + t;
        btab[tgt[j]] = stage[j];
    }
}

__global__ __launch_bounds__(256) void k_p3(const u32* __restrict__ km, const u32* __restrict__ btab,
        int* __restrict__ rowptr, int* __restrict__ ssrc){
    __shared__ u32 fh[DPB], fo[DPB];
    __shared__ u32 red[256];
    __shared__ int sst[CAP];
    int t = threadIdx.x, b = blockIdx.x;
    u32 basep = km[(size_t)b*P_BLOCKS];
    u32 endp  = km[(size_t)(b+1)*P_BLOCKS];
    int cnt = (int)(endp - basep);
    #pragma unroll
    for (int i=t;i<DPB;i+=256) fh[i] = 0;
    __syncthreads();
    for (int j=t; j<cnt; j+=256){
        u32 p = btab[basep + j];
        atomicAdd(&fh[p & 1023], 1);
    }
    __syncthreads();
    u32 v0=fh[4*t], v1=fh[4*t+1], v2=fh[4*t+2], v3=fh[4*t+3];
    u32 s4 = v0+v1+v2+v3; red[t] = s4; __syncthreads();
    for (int off=1; off<256; off<<=1){
        u32 xv = (t>=off)? red[t-off] : 0; __syncthreads();
        red[t] += xv; __syncthreads();
    }
    u32 excl = red[t] - s4;
    fo[4*t]=excl; fo[4*t+1]=excl+v0; fo[4*t+2]=excl+v0+v1; fo[4*t+3]=excl+v0+v1+v2;
    __syncthreads();
    #pragma unroll
    for (int i=t;i<DPB;i+=256) rowptr[b*DPB + i] = (int)(basep + fo[i]);
    if (b == BKTS-1 && t == 0) rowptr[N_NODES] = (int)endp;
    __syncthreads();
    for (int j=t; j<cnt; j+=256){
        u32 p = btab[basep + j];
        u32 pos = atomicAdd(&fo[p & 1023], 1);
        if (pos < (u32)CAP) sst[pos] = (int)(p >> 10);
    }
    __syncthreads();
    for (int j=t; j<cnt; j+=256) ssrc[basep + j] = sst[j];
}

// ---------------- GAT layer-1 node linear ----------------
__global__ __launch_bounds__(256) void k_linear1(const void* __restrict__ x,
        const void* __restrict__ W1, const void* __restrict__ asw, const void* __restrict__ adw,
        u16* __restrict__ h1, float* __restrict__ ad1, u32* __restrict__ gkey,
        const int* __restrict__ flag){
    int is32 = *flag;
    __shared__ float Wf[196], av[14], dv[14];
    __shared__ float red[256];
    int t = threadIdx.x;
    if (t < 196) Wf[t] = gload(W1, t, is32);
    else if (t < 210) av[t-196] = gload(asw, t-196, is32);
    else if (t < 224) dv[t-210] = gload(adw, t-210, is32);
    __syncthreads();
    int i = blockIdx.x*256 + t;
    float xv[14];
    if (is32){
        const float* xr = (const float*)x + (size_t)i*14;
        #pragma unroll
        for (int k=0;k<14;k++) xv[k] = xr[k];
    } else {
        const u32* xr = (const u32*)((const u16*)x + (size_t)i*14);
        #pragma unroll
        for (int p=0;p<7;p++){ u32 u = xr[p]; xv[2*p]=lo2f(u); xv[2*p+1]=hi2f(u); }
    }
    float h[14];
    #pragma unroll
    for (int j=0;j<14;j++){ float s=0.f;
        #pragma unroll
        for (int k=0;k<14;k++) s += xv[k]*Wf[k*14+j];
        h[j]=s; }
    float a=0.f, d=0.f;
    #pragma unroll
    for (int j=0;j<14;j++){ a += h[j]*av[j]; d += h[j]*dv[j]; }
    ad1[i]=d;
    u32 ou[8];
    #pragma unroll
    for (int p=0;p<7;p++) ou[p] = (u32)f2bf(h[2*p]) | ((u32)f2bf(h[2*p+1])<<16);
    __builtin_memcpy(&ou[7], &a, 4);
    uint4* hp = (uint4*)(h1 + (size_t)i*16);
    hp[0] = make_uint4(ou[0],ou[1],ou[2],ou[3]);
    hp[1] = make_uint4(ou[4],ou[5],ou[6],ou[7]);
    red[t] = a; __syncthreads();
    for (int o=128;o;o>>=1){ if (t<o) red[t]=fmaxf(red[t],red[t+o]); __syncthreads(); }
    if (t==0) atomicMax(gkey, fmax_key(red[0]));
}

// ---------------- gather1: layer-1 aggregate + epilogue computes layer-2 scores ----------------
__global__ __launch_bounds__(256) void k_gather1(const int* __restrict__ rowptr, const int* __restrict__ ssrc,
        const u16* __restrict__ h1, const float* __restrict__ ad1, const u32* __restrict__ gkey1,
        const void* __restrict__ b1, const float* __restrict__ prep,
        u16* __restrict__ g1, float* __restrict__ ad2, u32* __restrict__ gkey2,
        const int* __restrict__ flag){
    int is32 = *flag;
    __shared__ float b1s[14], vas[14], vds[14];
    __shared__ float red[256];
    int t = threadIdx.x;
    if (t < 14) b1s[t] = gload(b1, t, is32);
    else if (t < 28) vas[t-14] = prep[t-14];
    else if (t < 42) vds[t-28] = prep[t-28+14];
    __syncthreads();
    int i = blockIdx.x*256 + t;
    float adv = ad1[i];
    float M = lrelu(key_fmax(*gkey1) + adv);
    int beg = rowptr[i], end = rowptr[i+1];
    float acc[14] = {0,0,0,0,0,0,0,0,0,0,0,0,0,0};
    float den = 0.f;
    {   // self loop
        const uint4* hp = (const uint4*)(h1 + (size_t)i*16);
        edge_acc(hp[0], hp[1], adv, M, acc, den);
    }
    int j = beg;
    for (; j+4 <= end; j += 4){
        int s4[4];
        #pragma unroll
        for (int k=0;k<4;k++) s4[k] = __builtin_nontemporal_load(ssrc + j + k);
        uint4 r0[4], r1[4];
        #pragma unroll
        for (int k=0;k<4;k++){
            const uint4* hp = (const uint4*)(h1 + (size_t)s4[k]*16);
            r0[k] = hp[0]; r1[k] = hp[1];
        }
        #pragma unroll
        for (int k=0;k<4;k++) edge_acc(r0[k], r1[k], adv, M, acc, den);
    }
    for (; j<end; j++){
        int s = __builtin_nontemporal_load(ssrc + j);
        const uint4* hp = (const uint4*)(h1 + (size_t)s*16);
        edge_acc(hp[0], hp[1], adv, M, acc, den);
    }
    float inv = 1.0f/den;
    float v[14];
    #pragma unroll
    for (int f=0;f<14;f++) v[f] = fmaxf(acc[f]*inv + b1s[f], 0.f);
    float a2=0.f, d2=0.f;
    #pragma unroll
    for (int f=0;f<14;f++){ a2 += v[f]*vas[f]; d2 += v[f]*vds[f]; }
    ad2[i] = d2;
    u32 ou[8];
    #pragma unroll
    for (int p=0;p<7;p++) ou[p] = (u32)f2bf(v[2*p]) | ((u32)f2bf(v[2*p+1])<<16);
    __builtin_memcpy(&ou[7], &a2, 4);
    uint4* gp = (uint4*)(g1 + (size_t)i*16);
    gp[0]=make_uint4(ou[0],ou[1],ou[2],ou[3]);
    gp[1]=make_uint4(ou[4],ou[5],ou[6],ou[7]);
    red[t] = a2; __syncthreads();
    for (int o=128;o;o>>=1){ if (t<o) red[t]=fmaxf(red[t],red[t+o]); __syncthreads(); }
    if (t==0) atomicMax(gkey2, fmax_key(red[0]));
}

// ---------------- gather2: aggregate in 14-dim g1 space, then x@W2 + b2 + relu ----------------
__global__ __launch_bounds__(256) void k_gather2(const int* __restrict__ rowptr, const int* __restrict__ ssrc,
        const u16* __restrict__ g1, const float* __restrict__ ad2, const u32* __restrict__ gkey2,
        const void* __restrict__ W2, const void* __restrict__ b2, u16* __restrict__ g2,
        const int* __restrict__ flag){
    int is32 = *flag;
    __shared__ float W2s[448], b2s[32];
    int t = threadIdx.x;
    for (int idx=t; idx<448; idx+=256) W2s[idx] = gload(W2, idx, is32);
    if (t < 32) b2s[t] = gload(b2, t, is32);
    __syncthreads();
    int i = blockIdx.x*256 + t;
    float adv = ad2[i];
    float M = lrelu(key_fmax(*gkey2) + adv);
    int beg = rowptr[i], end = rowptr[i+1];
    float acc[14] = {0,0,0,0,0,0,0,0,0,0,0,0,0,0};
    float den = 0.f;
    {
        const uint4* hp = (const uint4*)(g1 + (size_t)i*16);
        edge_acc(hp[0], hp[1], adv, M, acc, den);
    }
    int j = beg;
    for (; j+4 <= end; j += 4){
        int s4[4];
        #pragma unroll
        for (int k=0;k<4;k++) s4[k] = __builtin_nontemporal_load(ssrc + j + k);
        uint4 r0[4], r1[4];
        #pragma unroll
        for (int k=0;k<4;k++){
            const uint4* hp = (const uint4*)(g1 + (size_t)s4[k]*16);
            r0[k] = hp[0]; r1[k] = hp[1];
        }
        #pragma unroll
        for (int k=0;k<4;k++) edge_acc(r0[k], r1[k], adv, M, acc, den);
    }
    for (; j<end; j++){
        int s = __builtin_nontemporal_load(ssrc + j);
        const uint4* hp = (const uint4*)(g1 + (size_t)s*16);
        edge_acc(hp[0], hp[1], adv, M, acc, den);
    }
    float inv = 1.0f/den;
    float an[14];
    #pragma unroll
    for (int f=0;f<14;f++) an[f] = acc[f]*inv;
    uint4* orow = (uint4*)(g2 + (size_t)i*32);
    #pragma unroll
    for (int g=0; g<4; g++){
        u32 ou[4];
        #pragma unroll
        for (int p=0;p<4;p++){
            int j0 = g*8 + 2*p;
            float va_ = b2s[j0], vb_ = b2s[j0+1];
            #pragma unroll
            for (int k=0;k<14;k++){ va_ += an[k]*W2s[k*32+j0]; vb_ += an[k]*W2s[k*32+j0+1]; }
            va_ = fmaxf(va_, 0.f); vb_ = fmaxf(vb_, 0.f);
            ou[p] = (u32)f2bf(va_) | ((u32)f2bf(vb_)<<16);
        }
        orow[g] = make_uint4(ou[0],ou[1],ou[2],ou[3]);
    }
}

// ---------------- pool (batch is sorted; binary search per graph) ----------------
__device__ __forceinline__ int lbound(const int* __restrict__ a, int n, int v){
    int lo=0, hi=n;
    while (lo < hi){ int m = (lo+hi)>>1; if (a[m] < v) lo = m+1; else hi = m; }
    return lo;
}

__global__ __launch_bounds__(64) void k_pool(const u16* __restrict__ g2, const int* __restrict__ batch,
        u16* __restrict__ comb, int N_){
    int b = blockIdx.x;
    int t = threadIdx.x, f = t & 31, half = t >> 5;
    int lo = lbound(batch, N_, b);
    int hi = lbound(batch, N_, b+1);
    float acc = 0.f;
    for (int i = lo + half; i < hi; i += 2) acc += bf2f(g2[(size_t)i*32 + f]);
    acc += __shfl_xor(acc, 32);
    if (t < 32) comb[(size_t)b*432 + f] = f2bf(acc);
}

// ---------------- weight transpose ----------------
__global__ __launch_bounds__(256) void k_transpose(const void* __restrict__ W, u16* __restrict__ Wt,
        int K, int Kp, int Nc, const int* __restrict__ flag){
    int is32 = *flag;
    int idx = blockIdx.x*256 + threadIdx.x;
    if (idx >= Nc*Kp) return;
    int n = idx / Kp, k = idx - n*Kp;
    Wt[idx] = (k < K) ? f2bf(gload(W, k*Nc + n, is32)) : (u16)0;
}

// ---------------- fused GEMM + bias + BN + ReLU (bf16 MFMA, 128x128 tile) ----------------
__global__ __launch_bounds__(256) void k_gemm(const void* __restrict__ A, const u16* __restrict__ Wt,
        const void* __restrict__ bias, const void* __restrict__ bnp, void* __restrict__ out,
        int K, int Kp, int Nc, int ostride, int ooff, int do_relu,
        int out32, const int* __restrict__ flag){
    int is32 = *flag;
    __shared__ u16 As[128][40];
    __shared__ u16 Bs[128][40];
    int t = threadIdx.x;
    int lane = t & 63, wave = t >> 6;
    int bm = blockIdx.x * 128;
    int bn = blockIdx.y * 128;
    int mt = (wave & 1) * 64, nt = (wave >> 1) * 64;
    int quad = lane >> 4, fr = lane & 15;

    f32x4 zero = {0.f, 0.f, 0.f, 0.f};
    f32x4 acc[4][4];
    #pragma unroll
    for (int i=0;i<4;i++)
        #pragma unroll
        for (int j=0;j<4;j++) acc[i][j] = zero;

    int srow0 = t >> 2;
    int scol = (t & 3) * 8;

    for (int k0 = 0; k0 < Kp; k0 += 32){
        #pragma unroll
        for (int h2_=0; h2_<2; h2_++){
            int row = srow0 + h2_*64;
            int gk = k0 + scol;
            uint4 av = make_uint4(0,0,0,0);
            if (gk + 8 <= K) av = *(const uint4*)((const u16*)A + (size_t)(bm+row)*K + gk);
            *(uint4*)(&As[row][scol]) = av;
            uint4 bv = make_uint4(0,0,0,0);
            if (bn + row < Nc) bv = *(const uint4*)(Wt + (size_t)(bn+row)*Kp + gk);
            *(uint4*)(&Bs[row][scol]) = bv;
        }
        __syncthreads();
        bf16x8 af[4], bfr[4];
        #pragma unroll
        for (int i=0;i<4;i++) af[i] = *(const bf16x8*)(&As[mt + i*16 + fr][quad*8]);
        #pragma unroll
        for (int j=0;j<4;j++) bfr[j] = *(const bf16x8*)(&Bs[nt + j*16 + fr][quad*8]);
        #pragma unroll
        for (int i=0;i<4;i++)
            #pragma unroll
            for (int j=0;j<4;j++)
                acc[i][j] = __builtin_amdgcn_mfma_f32_16x16x32_bf16(af[i], bfr[j], acc[i][j], 0, 0, 0);
        __syncthreads();
    }

    #pragma unroll
    for (int j=0;j<4;j++){
        int gn = bn + nt + j*16 + fr;
        if (gn >= Nc) continue;
        float bb = gload(bias, gn, is32);
        float scale = 1.f, shift = bb;
        if (bnp){
            float gm_ = gload(bnp, gn, is32), bt = gload(bnp, Nc+gn, is32);
            float mn = gload(bnp, 2*Nc+gn, is32), vr = gload(bnp, 3*Nc+gn, is32);
            scale = gm_ * rsqrtf(vr + 1e-5f);
            shift = (bb - mn)*scale + bt;
        }
        #pragma unroll
        for (int i=0;i<4;i++){
            #pragma unroll
            for (int r=0;r<4;r++){
                int gm = bm + mt + i*16 + quad*4 + r;
                float v = acc[i][j][r]*scale + shift;
                if (do_relu) v = fmaxf(v, 0.f);
                size_t oidx = (size_t)gm*ostride + ooff + gn;
                if (out32) ((float*)out)[oidx] = v;
                else       ((u16*)out)[oidx] = f2bf(v);
            }
        }
    }
}

// ---------------- final fcc2 (K=100, Nc=1) -> FP32 output ----------------
__global__ __launch_bounds__(256) void k_fcc2(const float* __restrict__ c1, const void* __restrict__ w,
        const void* __restrict__ b, float* __restrict__ outp, const int* __restrict__ flag){
    int is32 = *flag;
    __shared__ float wf[100];
    int t = threadIdx.x;
    if (t < 100) wf[t] = gload(w, t, is32);
    __syncthreads();
    int i = blockIdx.x*256 + t;
    const float* r = c1 + (size_t)i*100;
    float s = 0.f;
    #pragma unroll 4
    for (int k=0;k<100;k++) s += r[k]*wf[k];
    outp[i] = s + gload(b, 0, is32);
}

extern "C" void kernel_launch(void* const* d_in, const int* in_sizes, int n_in,
                              void* d_out, int out_size, void* d_ws, size_t ws_size,
                              hipStream_t stream){
    const int N = N_NODES, E = N_EDGES;
    const void* x    = d_in[0];
    const int* ei   = (const int*)d_in[1];
    const int* srcA = ei;
    const int* dstA = ei + E;
    const int* batch= (const int*)d_in[2];
    const void* fing = d_in[3];
    const void* tv   = d_in[4];
    const void* W1   = d_in[5];
    const void* as1w = d_in[6];
    const void* ad1w = d_in[7];
    const void* b1   = d_in[8];
    const void* W2   = d_in[9];
    const void* as2w = d_in[10];
    const void* ad2w = d_in[11];
    const void* b2   = d_in[12];
    const void* fc1w = d_in[13]; const void* fc1b = d_in[14]; const void* bn1 = d_in[15];
    const void* fc2w = d_in[16]; const void* fc2b = d_in[17]; const void* bn2 = d_in[18];
    const void* fc3w = d_in[19]; const void* fc3b = d_in[20]; const void* bn3 = d_in[21];
    const void* fc4w = d_in[22]; const void* fc4b = d_in[23]; const void* bn4 = d_in[24];
    const void* fccw = d_in[25]; const void* fccb = d_in[26]; const void* bnc = d_in[27];
    const void* fcc2w= d_in[28]; const void* fcc2b= d_in[29];

    char* ws = (char*)d_ws;
    size_t off = 0;
    auto alloc = [&](size_t bytes)->char*{ char* p = ws + off; off = (off + bytes + 255) & ~(size_t)255; return p; };
    int*  flagp  = (int*)alloc(256);          // [0]=dtype; [1]=gkey1; [2]=gkey2; +16B: prep[28]
    u32*  gkey1  = (u32*)flagp + 1;
    u32*  gkey2  = (u32*)flagp + 2;
    float* prep  = (float*)((char*)flagp + 16);
    int*  rowptr = (int*)alloc((size_t)(N+1)*4);
    int*  bsums  = (int*)alloc(513*4);
    u32*  tbl_bm = (u32*)alloc((size_t)BKTS*P_BLOCKS*4);
    u32*  tbl_km = (u32*)alloc(((size_t)BKTS*P_BLOCKS+1)*4);
    int*  ssrc   = (int*)alloc((size_t)E*4);       // 16 MB; comb aliases after gathers
    u16*  h1     = (u16*)alloc((size_t)N*16*2);    // 16.8 MB; fing_bf aliases h1+g1 after gather2
    u16*  g1     = (u16*)alloc((size_t)N*16*2);    // 16.8 MB
    float* ad1_  = (float*)alloc((size_t)N*4);
    float* ad2_  = (float*)alloc((size_t)N*4);
    char* scr32  = alloc((size_t)N*32*2);          // 33.6 MB: btab -> g2 -> fp1/tv1
    float* c1    = (float*)alloc((size_t)N_GRAPH*100*4);
    u16*  Wt1    = (u16*)alloc((size_t)400*1024*2);
    u16*  Wt2    = (u16*)alloc((size_t)200*416*2);
    u16*  Wt3    = (u16*)alloc((size_t)400*256*2);
    u16*  Wt4    = (u16*)alloc((size_t)200*416*2);
    u16*  Wtc    = (u16*)alloc((size_t)100*448*2);
    u16*  tv_bf  = (u16*)alloc((size_t)N_GRAPH*256*2);
    u32*  btab   = (u32*)scr32;                     // 16 MB during CSR build
    u16*  g2     = (u16*)scr32;                     // N*32 bf16 after gather2
    u16*  fp1    = (u16*)scr32;                     // 12.5 MB at gemm time (g2 dead)
    u16*  tv1    = (u16*)scr32 + (size_t)N_GRAPH*400;
    u16*  comb   = (u16*)ssrc;                      // 13.5 MB after gathers
    u16*  fing_bf= h1;                              // 33.6 MB spans h1+g1 after gather2

    (void)hipMemsetAsync(flagp, 0, 256, stream);

    k_detect <<<1, 256, 0, stream>>>((const u32*)x, flagp);
    k_prep   <<<1, 64, 0, stream>>>(W2, as2w, ad2w, prep, flagp);
    k_cast   <<<(N_GRAPH*256/8+255)/256, 256, 0, stream>>>(tv, tv_bf, N_GRAPH*256/8, flagp);

    // CSR build: bucketed counting sort, no global atomics
    k_p1   <<<P_BLOCKS, 256, 0, stream>>>(dstA, tbl_bm);
    k_ttbl <<<dim3(32,16), 256, 0, stream>>>(tbl_bm, tbl_km);
    k_scan1<<<512,  256, 0, stream>>>((int*)tbl_km, bsums);
    k_scan2<<<1,    256, 0, stream>>>(bsums);
    k_scan3<<<(BKTS*P_BLOCKS)/256, 256, 0, stream>>>((int*)tbl_km, bsums, BKTS*P_BLOCKS, E);
    k_p2   <<<P_BLOCKS, 256, 0, stream>>>(srcA, dstA, tbl_km, btab);
    k_p3   <<<BKTS, 256, 0, stream>>>(tbl_km, btab, rowptr, ssrc);

    k_linear1<<<N/256, 256, 0, stream>>>(x, W1, as1w, ad1w, h1, ad1_, gkey1, flagp);
    k_gather1<<<N/256, 256, 0, stream>>>(rowptr, ssrc, h1, ad1_, gkey1, b1, prep, g1, ad2_, gkey2, flagp);
    k_gather2<<<N/256, 256, 0, stream>>>(rowptr, ssrc, g1, ad2_, gkey2, W2, b2, g2, flagp);
    k_cast   <<<(N_GRAPH*1024/8+255)/256, 256, 0, stream>>>(fing, fing_bf, N_GRAPH*1024/8, flagp);
    k_pool   <<<N_GRAPH, 64, 0, stream>>>(g2, batch, comb, N);

    k_transpose<<<(400*1024+255)/256, 256, 0, stream>>>(fc1w, Wt1, 1024, 1024, 400, flagp);
    k_transpose<<<(200*416 +255)/256, 256, 0, stream>>>(fc2w, Wt2,  400,  416, 200, flagp);
    k_transpose<<<(400*256 +255)/256, 256, 0, stream>>>(fc3w, Wt3,  256,  256, 400, flagp);
    k_transpose<<<(200*416 +255)/256, 256, 0, stream>>>(fc4w, Wt4,  400,  416, 200, flagp);
    k_transpose<<<(100*448 +255)/256, 256, 0, stream>>>(fccw, Wtc,  432,  448, 100, flagp);

    k_gemm<<<dim3(128,4), 256, 0, stream>>>(fing_bf, Wt1, fc1b, bn1, fp1, 1024, 1024, 400, 400,   0, 1, 0, flagp);
    k_gemm<<<dim3(128,2), 256, 0, stream>>>(fp1,  Wt2, fc2b, bn2, comb, 400,  416, 200, 432,  32, 1, 0, flagp);
    k_gemm<<<dim3(128,4), 256, 0, stream>>>(tv_bf, Wt3, fc3b, bn3, tv1, 256,  256, 400, 400,   0, 1, 0, flagp);
    k_gemm<<<dim3(128,2), 256, 0, stream>>>(tv1,  Wt4, fc4b, bn4, comb, 400,  416, 200, 432, 232, 1, 0, flagp);
    k_gemm<<<dim3(128,1), 256, 0, stream>>>(comb, Wtc, fccb, bnc, c1,   432,  448, 100, 100,   0, 1, 1, flagp);

    k_fcc2<<<N_GRAPH/256, 256, 0, stream>>>(c1, fcc2w, fcc2b, (float*)d_out, flagp);
}